// Round 1
// baseline (2136.612 us; speedup 1.0000x reference)
//
#include <hip/hip_runtime.h>
#include <hip/hip_bf16.h>
#include <math.h>

// ---- problem constants ----
static constexpr int NN  = 1024;
static constexpr int KK  = 16;
static constexpr int C0c = 128;
static constexpr int C1c = 32;
static constexpr int EDc = 64;
static constexpr int Hc  = 4;
static constexpr int Lc  = 2;
#define SCALE_ATTN 0.13363062095621219f  /* 1/sqrt(32+3*8) = 1/sqrt(56) */

__device__ __forceinline__ float wsum64(float v) {
    for (int o = 32; o > 0; o >>= 1) v += __shfl_xor(v, o);
    return v;
}
__device__ __forceinline__ float gsum16(float v) {
    for (int o = 8; o > 0; o >>= 1) v += __shfl_xor(v, o, 16);
    return v;
}
__device__ __forceinline__ float gmax16(float v) {
    for (int o = 8; o > 0; o >>= 1) v = fmaxf(v, __shfl_xor(v, o, 16));
    return v;
}
__device__ __forceinline__ float gelu_f(float x) {
    float x3 = x * x * x;
    return 0.5f * x * (1.0f + tanhf(0.7978845608028654f * (x + 0.044715f * x3)));
}

// ---------------- kNN (one block per node) ----------------
__global__ __launch_bounds__(256) void knn_kernel(const float* __restrict__ coords,
                                                  int* __restrict__ idx,
                                                  float* __restrict__ maskf,
                                                  float* __restrict__ y1) {
    __shared__ float ca[NN * 3];
    __shared__ float d2s[NN];
    __shared__ float rv[256];
    __shared__ int   ri[256];
    const int n = blockIdx.x, tid = threadIdx.x;
    for (int i = tid; i < NN; i += 256) {
        ca[i * 3 + 0] = coords[(i * 4 + 1) * 3 + 0];
        ca[i * 3 + 1] = coords[(i * 4 + 1) * 3 + 1];
        ca[i * 3 + 2] = coords[(i * 4 + 1) * 3 + 2];
    }
    __syncthreads();
    const float cx = ca[n * 3 + 0], cy = ca[n * 3 + 1], cz = ca[n * 3 + 2];
    for (int i = tid; i < NN; i += 256) {
        float dx = cx - ca[i * 3 + 0], dy = cy - ca[i * 3 + 1], dz = cz - ca[i * 3 + 2];
        float d2 = dx * dx + dy * dy + dz * dz;
        d2s[i] = (i == n) ? 1e9f : d2;
    }
    __syncthreads();
    for (int t = 0; t < KK; ++t) {
        float best = 1e30f; int bi = NN;
        for (int i = tid; i < NN; i += 256) {
            float v = d2s[i];
            if (v < best) { best = v; bi = i; }
        }
        rv[tid] = best; ri[tid] = bi;
        __syncthreads();
        for (int s = 128; s > 0; s >>= 1) {
            if (tid < s) {
                float ov = rv[tid + s]; int oi = ri[tid + s];
                if (ov < rv[tid] || (ov == rv[tid] && oi < ri[tid])) { rv[tid] = ov; ri[tid] = oi; }
            }
            __syncthreads();
        }
        if (tid == 0) {
            int j = ri[0];
            idx[n * KK + t] = j;
            float dist = sqrtf(rv[0]);
            maskf[n * KK + t] = (dist <= 16.0f) ? 1.0f : 0.0f;
            float rx = ca[j * 3 + 0] - cx, ry = ca[j * 3 + 1] - cy, rz = ca[j * 3 + 2] - cz;
            float nrm = sqrtf(rx * rx + ry * ry + rz * rz) + 1e-6f;
            y1[(n * KK + t) * 3 + 0] = rx / nrm;
            y1[(n * KK + t) * 3 + 1] = ry / nrm;
            y1[(n * KK + t) * 3 + 2] = rz / nrm;
            d2s[j] = 2e30f;
        }
        __syncthreads();
    }
}

// ---------------- edge gather + LayerNorm (one wave per edge) ----------------
__global__ __launch_bounds__(256) void edge_ln_kernel(const float* __restrict__ pair,
                                                      const int* __restrict__ idx,
                                                      const float* __restrict__ g,
                                                      const float* __restrict__ b,
                                                      float* __restrict__ edges) {
    const int wid = threadIdx.x >> 6, lane = threadIdx.x & 63;
    const int e = blockIdx.x * 4 + wid;
    const int n = e >> 4;
    const int j = idx[e];
    float v = pair[((size_t)n * NN + j) * EDc + lane];
    float m = wsum64(v) * (1.0f / 64.0f);
    float d = v - m;
    float var = wsum64(d * d) * (1.0f / 64.0f);
    edges[e * EDc + lane] = d * rsqrtf(var + 1e-5f) * g[lane] + b[lane];
}

// ---------------- input projection (one wave per node) ----------------
__global__ __launch_bounds__(256) void init_kernel(const float* __restrict__ nf,
                                                   const float* __restrict__ coords,
                                                   const float* __restrict__ Wi0,
                                                   const float* __restrict__ Wi1,
                                                   float* __restrict__ f0,
                                                   float* __restrict__ f1) {
    __shared__ float xs[4][128];
    const int wid = threadIdx.x >> 6, lane = threadIdx.x & 63;
    const int n = blockIdx.x * 4 + wid;
    xs[wid][lane]      = nf[n * 128 + lane];
    xs[wid][lane + 64] = nf[n * 128 + lane + 64];
    __syncthreads();
    for (int t = 0; t < 2; ++t) {
        int o = lane + 64 * t;
        const float* w = Wi0 + o * 128;
        float acc = 0.f;
        for (int c = 0; c < 128; ++c) acc += w[c] * xs[wid][c];
        f0[n * 128 + o] = acc;
    }
    if (lane < 32) {
        int c = lane;
        float w0 = Wi1[c * 3 + 0], w1 = Wi1[c * 3 + 1], w2 = Wi1[c * 3 + 2];
        for (int m = 0; m < 3; ++m) {
            float cav = coords[(n * 4 + 1) * 3 + m];
            float a0 = coords[(n * 4 + 0) * 3 + m] - cav;  // N
            float a1 = coords[(n * 4 + 2) * 3 + m] - cav;  // C
            float a2 = coords[(n * 4 + 3) * 3 + m] - cav;  // O
            f1[(n * 32 + c) * 3 + m] = w0 * a0 + w1 * a1 + w2 * a2;
        }
    }
}

// ---------------- fiber norm (+ optional q projection) (one wave per node) ----------------
__global__ __launch_bounds__(256) void fnorm_kernel(const float* __restrict__ f0,
                                                    const float* __restrict__ f1,
                                                    const float* __restrict__ g0,
                                                    const float* __restrict__ b0,
                                                    const float* __restrict__ g1,
                                                    const float* __restrict__ b1,
                                                    const float* __restrict__ Wq0,
                                                    const float* __restrict__ Wq1,
                                                    float* __restrict__ x0,
                                                    float* __restrict__ x1,
                                                    float* __restrict__ q0,
                                                    float* __restrict__ q1) {
    __shared__ float x0s[4][128];
    __shared__ float x1s[4][96];
    const int wid = threadIdx.x >> 6, lane = threadIdx.x & 63;
    const int n = blockIdx.x * 4 + wid;
    float va = f0[n * 128 + lane], vb = f0[n * 128 + lane + 64];
    float m = wsum64(va + vb) * (1.0f / 128.0f);
    float da = va - m, db = vb - m;
    float var = wsum64(da * da + db * db) * (1.0f / 128.0f);
    float rs = rsqrtf(var + 1e-5f);
    float xa = gelu_f(da * rs * g0[lane] + b0[lane]);
    float xb = gelu_f(db * rs * g0[lane + 64] + b0[lane + 64]);
    x0s[wid][lane] = xa; x0s[wid][lane + 64] = xb;
    x0[n * 128 + lane] = xa; x0[n * 128 + lane + 64] = xb;
    // degree-1 phase-preserving norm (lanes duplicate c = lane&31 for the 32-wide stats)
    int c = lane & 31;
    float h0 = f1[(n * 32 + c) * 3 + 0], h1 = f1[(n * 32 + c) * 3 + 1], h2 = f1[(n * 32 + c) * 3 + 2];
    float n1 = sqrtf(h0 * h0 + h1 * h1 + h2 * h2);
    float ms = wsum64(n1) * (1.0f / 64.0f);          // = mean over 32 (values duplicated 2x)
    float dd = n1 - ms;
    float vv = wsum64(dd * dd) * (1.0f / 64.0f);
    float sc = gelu_f(dd * rsqrtf(vv + 1e-5f) * g1[c] + b1[c]) / (n1 + 1e-6f);
    if (lane < 32) {
        float o0v = h0 * sc, o1v = h1 * sc, o2v = h2 * sc;
        x1s[wid][c * 3 + 0] = o0v; x1s[wid][c * 3 + 1] = o1v; x1s[wid][c * 3 + 2] = o2v;
        x1[(n * 32 + c) * 3 + 0] = o0v; x1[(n * 32 + c) * 3 + 1] = o1v; x1[(n * 32 + c) * 3 + 2] = o2v;
    }
    __syncthreads();
    if (Wq0 != nullptr) {
        for (int t = 0; t < 2; ++t) {
            int o = lane + 64 * t;
            const float* w = Wq0 + o * 128;
            float acc = 0.f;
            for (int cc = 0; cc < 128; ++cc) acc += w[cc] * x0s[wid][cc];
            q0[n * 128 + o] = acc;
        }
        for (int val = lane; val < 96; val += 64) {
            int o = val & 31, mm = val >> 5;
            const float* w = Wq1 + o * 32;
            float acc = 0.f;
            for (int cc = 0; cc < 32; ++cc) acc += w[cc] * x1s[wid][cc * 3 + mm];
            q1[(n * 32 + o) * 3 + mm] = acc;
        }
    }
}

// ---------------- TFN edge kernel (radial proj fused) (one wave per edge) ----------------
__global__ __launch_bounds__(256) void tfn_kernel(const float* __restrict__ edges,
                                                  const float* __restrict__ x0,
                                                  const float* __restrict__ x1,
                                                  const int* __restrict__ idx,
                                                  const float* __restrict__ y1,
                                                  const float* __restrict__ Wr,   // [384,64]
                                                  const float* __restrict__ WA,   // [128,160]
                                                  const float* __restrict__ WB,   // [32,224]
                                                  float* __restrict__ k0,
                                                  float* __restrict__ k1) {
    __shared__ float es[4][64];
    __shared__ float x0js[4][128];
    __shared__ float x1js[4][96];
    __shared__ float dot1s[4][32];
    __shared__ float in0s[4][160];
    __shared__ float in1s[4][672];  // [224][3]
    const int wid = threadIdx.x >> 6, lane = threadIdx.x & 63;
    const int e = blockIdx.x * 4 + wid;
    const int j = idx[e];
    es[wid][lane] = edges[e * 64 + lane];
    x0js[wid][lane]      = x0[j * 128 + lane];
    x0js[wid][lane + 64] = x0[j * 128 + lane + 64];
    if (lane < 32) {
        x1js[wid][lane * 3 + 0] = x1[(j * 32 + lane) * 3 + 0];
        x1js[wid][lane * 3 + 1] = x1[(j * 32 + lane) * 3 + 1];
        x1js[wid][lane * 3 + 2] = x1[(j * 32 + lane) * 3 + 2];
    }
    const float ya = y1[e * 3 + 0], yb = y1[e * 3 + 1], yc = y1[e * 3 + 2];
    __syncthreads();
    if (lane < 32) {
        dot1s[wid][lane] = x1js[wid][lane * 3 + 0] * ya + x1js[wid][lane * 3 + 1] * yb
                         + x1js[wid][lane * 3 + 2] * yc;
    }
    __syncthreads();
    for (int t = 0; t < 6; ++t) {
        int row = lane + 64 * t;
        const float* w = Wr + row * 64;
        float acc = 0.f;
        for (int i = 0; i < 64; ++i) acc += w[i] * es[wid][i];
        if (row < 128) {
            in0s[wid][row] = acc * x0js[wid][row];
        } else if (row < 160) {
            int c = row - 128;
            in0s[wid][128 + c] = acc * dot1s[wid][c];
        } else if (row < 288) {
            int c = row - 160;
            float f = acc * x0js[wid][c];
            in1s[wid][c * 3 + 0] = f * ya; in1s[wid][c * 3 + 1] = f * yb; in1s[wid][c * 3 + 2] = f * yc;
        } else if (row < 320) {
            int c = row - 288;
            in1s[wid][(128 + c) * 3 + 0] = acc * x1js[wid][c * 3 + 0];
            in1s[wid][(128 + c) * 3 + 1] = acc * x1js[wid][c * 3 + 1];
            in1s[wid][(128 + c) * 3 + 2] = acc * x1js[wid][c * 3 + 2];
        } else if (row < 352) {
            int c = row - 320;
            float fx = x1js[wid][c * 3 + 0], fy = x1js[wid][c * 3 + 1], fz = x1js[wid][c * 3 + 2];
            in1s[wid][(160 + c) * 3 + 0] = acc * (fy * yc - fz * yb);
            in1s[wid][(160 + c) * 3 + 1] = acc * (fz * ya - fx * yc);
            in1s[wid][(160 + c) * 3 + 2] = acc * (fx * yb - fy * ya);
        } else {
            int c = row - 352;
            float d = dot1s[wid][c];
            in1s[wid][(192 + c) * 3 + 0] = acc * (ya * d - x1js[wid][c * 3 + 0] * (1.0f / 3.0f));
            in1s[wid][(192 + c) * 3 + 1] = acc * (yb * d - x1js[wid][c * 3 + 1] * (1.0f / 3.0f));
            in1s[wid][(192 + c) * 3 + 2] = acc * (yc * d - x1js[wid][c * 3 + 2] * (1.0f / 3.0f));
        }
    }
    __syncthreads();
    for (int t = 0; t < 2; ++t) {
        int o = lane + 64 * t;
        const float* w = WA + o * 160;
        float acc = 0.f;
        for (int c = 0; c < 160; ++c) acc += w[c] * in0s[wid][c];
        k0[e * 128 + o] = acc;
    }
    for (int val = lane; val < 96; val += 64) {
        int o = val & 31, m = val >> 5;
        const float* w = WB + o * 224;
        float acc = 0.f;
        for (int c = 0; c < 224; ++c) acc += w[c] * in1s[wid][c * 3 + m];
        k1[(e * 32 + o) * 3 + m] = acc;
    }
}

// ---------------- attention + output projection + residual (one wave per node) ----------------
__global__ __launch_bounds__(256) void attn_kernel(const float* __restrict__ q0,
                                                   const float* __restrict__ q1,
                                                   const float* __restrict__ k0,
                                                   const float* __restrict__ k1,
                                                   const float* __restrict__ v0,
                                                   const float* __restrict__ v1,
                                                   const float* __restrict__ edges,
                                                   const float* __restrict__ maskf,
                                                   const float* __restrict__ Wb,   // [4,64]
                                                   const float* __restrict__ Wo0,  // [128,128]
                                                   const float* __restrict__ Wo1,  // [32,32]
                                                   const float* __restrict__ alpha,
                                                   float* __restrict__ f0,
                                                   float* __restrict__ f1) {
    __shared__ float q0s[4][128];
    __shared__ float q1s[4][96];
    __shared__ float attns[4][64];
    __shared__ float o0s[4][128];
    __shared__ float o1s[4][96];
    const int wid = threadIdx.x >> 6, lane = threadIdx.x & 63;
    const int n = blockIdx.x * 4 + wid;
    q0s[wid][lane]      = q0[n * 128 + lane];
    q0s[wid][lane + 64] = q0[n * 128 + lane + 64];
    if (lane < 32) {
        q1s[wid][lane * 3 + 0] = q1[(n * 32 + lane) * 3 + 0];
        q1s[wid][lane * 3 + 1] = q1[(n * 32 + lane) * 3 + 1];
        q1s[wid][lane * 3 + 2] = q1[(n * 32 + lane) * 3 + 2];
    }
    __syncthreads();
    const int h = lane >> 4, k = lane & 15;
    const int e = n * KK + k;
    float acc = 0.f;
    for (int c = 0; c < 32; ++c) acc += q0s[wid][h * 32 + c] * k0[e * 128 + h * 32 + c];
    for (int c = 0; c < 8; ++c)
        for (int m = 0; m < 3; ++m)
            acc += q1s[wid][(h * 8 + c) * 3 + m] * k1[(e * 32 + h * 8 + c) * 3 + m];
    acc *= SCALE_ATTN;
    float bias = 0.f;
    for (int i = 0; i < 64; ++i) bias += Wb[h * 64 + i] * edges[e * 64 + i];
    acc += bias;
    if (maskf[e] == 0.0f) acc = -1e9f;
    float mx = gmax16(acc);
    float ex = expf(acc - mx);
    float sm = gsum16(ex);
    attns[wid][lane] = ex / sm;
    __syncthreads();
    for (int t = 0; t < 2; ++t) {
        int oc = lane + 64 * t;
        int h2 = oc >> 5;
        float a = 0.f;
        for (int kk = 0; kk < KK; ++kk) a += attns[wid][h2 * 16 + kk] * v0[(n * KK + kk) * 128 + oc];
        o0s[wid][oc] = a;
    }
    for (int val = lane; val < 96; val += 64) {
        int cc = val & 31, m = val >> 5;
        int h2 = cc >> 3;
        float a = 0.f;
        for (int kk = 0; kk < KK; ++kk) a += attns[wid][h2 * 16 + kk] * v1[((n * KK + kk) * 32 + cc) * 3 + m];
        o1s[wid][cc * 3 + m] = a;
    }
    __syncthreads();
    const float al = alpha[0];
    for (int t = 0; t < 2; ++t) {
        int o = lane + 64 * t;
        const float* w = Wo0 + o * 128;
        float a = 0.f;
        for (int c = 0; c < 128; ++c) a += w[c] * o0s[wid][c];
        f0[n * 128 + o] += al * a;
    }
    for (int val = lane; val < 96; val += 64) {
        int o = val & 31, m = val >> 5;
        const float* w = Wo1 + o * 32;
        float a = 0.f;
        for (int c = 0; c < 32; ++c) a += w[c] * o1s[wid][c * 3 + m];
        f1[(n * 32 + o) * 3 + m] += al * a;
    }
}

// ---------------- fiber feed-forward + residual (one wave per node) ----------------
__global__ __launch_bounds__(256) void ff_kernel(const float* __restrict__ x0,
                                                 const float* __restrict__ x1,
                                                 const float* __restrict__ Wf0a,  // [512,128]
                                                 const float* __restrict__ Wf0b,  // [128,512]
                                                 const float* __restrict__ Wf1a,  // [128,32]
                                                 const float* __restrict__ Wf1b,  // [32,128]
                                                 const float* __restrict__ alpha,
                                                 float* __restrict__ f0,
                                                 float* __restrict__ f1) {
    __shared__ float x0s[4][128];
    __shared__ float hs[4][512];
    __shared__ float x1s[4][96];
    __shared__ float h1s[4][384];
    const int wid = threadIdx.x >> 6, lane = threadIdx.x & 63;
    const int n = blockIdx.x * 4 + wid;
    x0s[wid][lane]      = x0[n * 128 + lane];
    x0s[wid][lane + 64] = x0[n * 128 + lane + 64];
    if (lane < 32) {
        x1s[wid][lane * 3 + 0] = x1[(n * 32 + lane) * 3 + 0];
        x1s[wid][lane * 3 + 1] = x1[(n * 32 + lane) * 3 + 1];
        x1s[wid][lane * 3 + 2] = x1[(n * 32 + lane) * 3 + 2];
    }
    __syncthreads();
    for (int t = 0; t < 8; ++t) {
        int r = lane + 64 * t;
        const float* w = Wf0a + r * 128;
        float a = 0.f;
        for (int c = 0; c < 128; ++c) a += w[c] * x0s[wid][c];
        hs[wid][r] = gelu_f(a);
    }
    for (int t = 0; t < 2; ++t) {
        int r = lane + 64 * t;
        const float* w = Wf1a + r * 32;
        float t0 = 0.f, t1 = 0.f, t2 = 0.f;
        for (int c = 0; c < 32; ++c) {
            float wv = w[c];
            t0 += wv * x1s[wid][c * 3 + 0];
            t1 += wv * x1s[wid][c * 3 + 1];
            t2 += wv * x1s[wid][c * 3 + 2];
        }
        float nh = sqrtf(t0 * t0 + t1 * t1 + t2 * t2);
        float sc = gelu_f(nh) / (nh + 1e-6f);
        h1s[wid][r * 3 + 0] = t0 * sc; h1s[wid][r * 3 + 1] = t1 * sc; h1s[wid][r * 3 + 2] = t2 * sc;
    }
    __syncthreads();
    const float al = alpha[0];
    for (int t = 0; t < 2; ++t) {
        int o = lane + 64 * t;
        const float* w = Wf0b + o * 512;
        float a = 0.f;
        for (int r = 0; r < 512; ++r) a += w[r] * hs[wid][r];
        f0[n * 128 + o] += al * a;
    }
    for (int val = lane; val < 96; val += 64) {
        int o = val & 31, m = val >> 5;
        const float* w = Wf1b + o * 128;
        float a = 0.f;
        for (int r = 0; r < 128; ++r) a += w[r] * h1s[wid][r * 3 + m];
        f1[(n * 32 + o) * 3 + m] += al * a;
    }
}

// ---------------- output projection (one wave per node) ----------------
__global__ __launch_bounds__(256) void out_kernel(const float* __restrict__ f0,
                                                  const float* __restrict__ f1,
                                                  const float* __restrict__ coords,
                                                  const float* __restrict__ Wp0,  // [128,128]
                                                  const float* __restrict__ Wp1,  // [3,32]
                                                  float* __restrict__ out) {
    __shared__ float f0s[4][128];
    const int wid = threadIdx.x >> 6, lane = threadIdx.x & 63;
    const int n = blockIdx.x * 4 + wid;
    f0s[wid][lane]      = f0[n * 128 + lane];
    f0s[wid][lane + 64] = f0[n * 128 + lane + 64];
    __syncthreads();
    for (int t = 0; t < 2; ++t) {
        int o = lane + 64 * t;
        const float* w = Wp0 + o * 128;
        float a = 0.f;
        for (int c = 0; c < 128; ++c) a += w[c] * f0s[wid][c];
        out[n * 128 + o] = a;
    }
    if (lane < 9) {
        int o = lane / 3, m = lane % 3;
        float a = coords[(n * 4 + 1) * 3 + m];
        const float* w = Wp1 + o * 32;
        for (int c = 0; c < 32; ++c) a += w[c] * f1[(n * 32 + c) * 3 + m];
        out[NN * 128 + (n * 3 + o) * 3 + m] = a;
    }
}

extern "C" void kernel_launch(void* const* d_in, const int* in_sizes, int n_in,
                              void* d_out, int out_size, void* d_ws, size_t ws_size,
                              hipStream_t stream) {
    (void)in_sizes; (void)n_in; (void)out_size; (void)ws_size;
    const float* node_feats = (const float*)d_in[0];
    const float* pair       = (const float*)d_in[1];
    const float* coords     = (const float*)d_in[2];
    const float* eln_g      = (const float*)d_in[3];
    const float* eln_b      = (const float*)d_in[4];
    const float* Wi0        = (const float*)d_in[5];
    const float* Wi1        = (const float*)d_in[6];
    const float* ln0_g      = (const float*)d_in[7];
    const float* ln0_b      = (const float*)d_in[8];
    const float* n1_g       = (const float*)d_in[9];
    const float* n1_b       = (const float*)d_in[10];
    const float* Wq0        = (const float*)d_in[11];
    const float* Wq1        = (const float*)d_in[12];
    const float* WrK        = (const float*)d_in[13];
    const float* WrV        = (const float*)d_in[14];
    const float* WkA        = (const float*)d_in[15];
    const float* WkB        = (const float*)d_in[16];
    const float* WvA        = (const float*)d_in[17];
    const float* WvB        = (const float*)d_in[18];
    const float* Wb         = (const float*)d_in[19];
    const float* Wo0        = (const float*)d_in[20];
    const float* Wo1        = (const float*)d_in[21];
    const float* alpha_attn = (const float*)d_in[22];
    const float* lnf0_g     = (const float*)d_in[23];
    const float* lnf0_b     = (const float*)d_in[24];
    const float* nf1_g      = (const float*)d_in[25];
    const float* nf1_b      = (const float*)d_in[26];
    const float* Wf0a       = (const float*)d_in[27];
    const float* Wf0b       = (const float*)d_in[28];
    const float* Wf1a       = (const float*)d_in[29];
    const float* Wf1b       = (const float*)d_in[30];
    const float* alpha_ff   = (const float*)d_in[31];
    const float* Wp0        = (const float*)d_in[32];
    const float* Wp1        = (const float*)d_in[33];
    float* out = (float*)d_out;

    float* ws = (float*)d_ws;
    size_t off = 0;
    int*   idx   = (int*)(ws + off); off += NN * KK;          // 16384
    float* maskf = ws + off;         off += NN * KK;          // 16384
    float* y1    = ws + off;         off += NN * KK * 3;      // 49152
    float* edges = ws + off;         off += (size_t)NN * KK * EDc;  // 1,048,576
    float* f0    = ws + off;         off += NN * C0c;         // 131072
    float* f1    = ws + off;         off += NN * C1c * 3;     // 98304
    float* x0    = ws + off;         off += NN * C0c;
    float* x1    = ws + off;         off += NN * C1c * 3;
    float* q0    = ws + off;         off += NN * C0c;
    float* q1    = ws + off;         off += NN * C1c * 3;
    float* k0    = ws + off;         off += (size_t)NN * KK * C0c;      // 2,097,152
    float* k1    = ws + off;         off += (size_t)NN * KK * C1c * 3;  // 1,572,864
    float* v0    = ws + off;         off += (size_t)NN * KK * C0c;
    float* v1    = ws + off;         off += (size_t)NN * KK * C1c * 3;

    knn_kernel<<<NN, 256, 0, stream>>>(coords, idx, maskf, y1);
    edge_ln_kernel<<<NN * KK / 4, 256, 0, stream>>>(pair, idx, eln_g, eln_b, edges);
    init_kernel<<<NN / 4, 256, 0, stream>>>(node_feats, coords, Wi0, Wi1, f0, f1);

    for (int l = 0; l < Lc; ++l) {
        fnorm_kernel<<<NN / 4, 256, 0, stream>>>(f0, f1,
            ln0_g + l * 128, ln0_b + l * 128, n1_g + l * 32, n1_b + l * 32,
            Wq0 + l * 128 * 128, Wq1 + l * 32 * 32, x0, x1, q0, q1);
        tfn_kernel<<<NN * KK / 4, 256, 0, stream>>>(edges, x0, x1, idx, y1,
            WrK + l * 384 * 64, WkA + l * 128 * 160, WkB + l * 32 * 224, k0, k1);
        tfn_kernel<<<NN * KK / 4, 256, 0, stream>>>(edges, x0, x1, idx, y1,
            WrV + l * 384 * 64, WvA + l * 128 * 160, WvB + l * 32 * 224, v0, v1);
        attn_kernel<<<NN / 4, 256, 0, stream>>>(q0, q1, k0, k1, v0, v1, edges, maskf,
            Wb + l * Hc * 64, Wo0 + l * 128 * 128, Wo1 + l * 32 * 32,
            alpha_attn + l, f0, f1);
        fnorm_kernel<<<NN / 4, 256, 0, stream>>>(f0, f1,
            lnf0_g + l * 128, lnf0_b + l * 128, nf1_g + l * 32, nf1_b + l * 32,
            nullptr, nullptr, x0, x1, nullptr, nullptr);
        ff_kernel<<<NN / 4, 256, 0, stream>>>(x0, x1,
            Wf0a + l * 512 * 128, Wf0b + l * 128 * 512,
            Wf1a + l * 128 * 32, Wf1b + l * 32 * 128,
            alpha_ff + l, f0, f1);
    }

    out_kernel<<<NN / 4, 256, 0, stream>>>(f0, f1, coords, Wp0, Wp1, out);
}

// Round 2
// 507.703 us; speedup vs baseline: 4.2084x; 4.2084x over previous
//
#include <hip/hip_runtime.h>
#include <hip/hip_bf16.h>
#include <math.h>

// ---- problem constants ----
static constexpr int NN  = 1024;
static constexpr int KK  = 16;
static constexpr int C0c = 128;
static constexpr int C1c = 32;
static constexpr int EDc = 64;
static constexpr int Hc  = 4;
static constexpr int Lc  = 2;
static constexpr int ENUM = NN * KK;   // 16384 edges
#define SCALE_ATTN 0.13363062095621219f  /* 1/sqrt(32+3*8) = 1/sqrt(56) */

__device__ __forceinline__ float wsum64(float v) {
    for (int o = 32; o > 0; o >>= 1) v += __shfl_xor(v, o);
    return v;
}
__device__ __forceinline__ float gsum16(float v) {
    for (int o = 8; o > 0; o >>= 1) v += __shfl_xor(v, o, 16);
    return v;
}
__device__ __forceinline__ float gmax16(float v) {
    for (int o = 8; o > 0; o >>= 1) v = fmaxf(v, __shfl_xor(v, o, 16));
    return v;
}
__device__ __forceinline__ float gelu_f(float x) {
    float x3 = x * x * x;
    return 0.5f * x * (1.0f + tanhf(0.7978845608028654f * (x + 0.044715f * x3)));
}

// ---------------- kNN (one block per node) ----------------
__global__ __launch_bounds__(256) void knn_kernel(const float* __restrict__ coords,
                                                  int* __restrict__ idx,
                                                  float* __restrict__ maskf,
                                                  float* __restrict__ y1) {
    __shared__ float ca[NN * 3];
    __shared__ float d2s[NN];
    __shared__ float rv[256];
    __shared__ int   ri[256];
    const int n = blockIdx.x, tid = threadIdx.x;
    for (int i = tid; i < NN; i += 256) {
        ca[i * 3 + 0] = coords[(i * 4 + 1) * 3 + 0];
        ca[i * 3 + 1] = coords[(i * 4 + 1) * 3 + 1];
        ca[i * 3 + 2] = coords[(i * 4 + 1) * 3 + 2];
    }
    __syncthreads();
    const float cx = ca[n * 3 + 0], cy = ca[n * 3 + 1], cz = ca[n * 3 + 2];
    for (int i = tid; i < NN; i += 256) {
        float dx = cx - ca[i * 3 + 0], dy = cy - ca[i * 3 + 1], dz = cz - ca[i * 3 + 2];
        float d2 = dx * dx + dy * dy + dz * dz;
        d2s[i] = (i == n) ? 1e9f : d2;
    }
    __syncthreads();
    for (int t = 0; t < KK; ++t) {
        float best = 1e30f; int bi = NN;
        for (int i = tid; i < NN; i += 256) {
            float v = d2s[i];
            if (v < best) { best = v; bi = i; }
        }
        rv[tid] = best; ri[tid] = bi;
        __syncthreads();
        for (int s = 128; s > 0; s >>= 1) {
            if (tid < s) {
                float ov = rv[tid + s]; int oi = ri[tid + s];
                if (ov < rv[tid] || (ov == rv[tid] && oi < ri[tid])) { rv[tid] = ov; ri[tid] = oi; }
            }
            __syncthreads();
        }
        if (tid == 0) {
            int j = ri[0];
            idx[n * KK + t] = j;
            float dist = sqrtf(rv[0]);
            maskf[n * KK + t] = (dist <= 16.0f) ? 1.0f : 0.0f;
            float rx = ca[j * 3 + 0] - cx, ry = ca[j * 3 + 1] - cy, rz = ca[j * 3 + 2] - cz;
            float nrm = sqrtf(rx * rx + ry * ry + rz * rz) + 1e-6f;
            y1[(n * KK + t) * 3 + 0] = rx / nrm;
            y1[(n * KK + t) * 3 + 1] = ry / nrm;
            y1[(n * KK + t) * 3 + 2] = rz / nrm;
            d2s[j] = 2e30f;
        }
        __syncthreads();
    }
}

// ---------------- edge gather + LayerNorm (one wave per edge) ----------------
__global__ __launch_bounds__(256) void edge_ln_kernel(const float* __restrict__ pair,
                                                      const int* __restrict__ idx,
                                                      const float* __restrict__ g,
                                                      const float* __restrict__ b,
                                                      float* __restrict__ edges) {
    const int wid = threadIdx.x >> 6, lane = threadIdx.x & 63;
    const int e = blockIdx.x * 4 + wid;
    const int n = e >> 4;
    const int j = idx[e];
    float v = pair[((size_t)n * NN + j) * EDc + lane];
    float m = wsum64(v) * (1.0f / 64.0f);
    float d = v - m;
    float var = wsum64(d * d) * (1.0f / 64.0f);
    edges[e * EDc + lane] = d * rsqrtf(var + 1e-5f) * g[lane] + b[lane];
}

// ---------------- input projection (one wave per node) ----------------
__global__ __launch_bounds__(256) void init_kernel(const float* __restrict__ nf,
                                                   const float* __restrict__ coords,
                                                   const float* __restrict__ Wi0,
                                                   const float* __restrict__ Wi1,
                                                   float* __restrict__ f0,
                                                   float* __restrict__ f1) {
    __shared__ float xs[4][128];
    const int wid = threadIdx.x >> 6, lane = threadIdx.x & 63;
    const int n = blockIdx.x * 4 + wid;
    xs[wid][lane]      = nf[n * 128 + lane];
    xs[wid][lane + 64] = nf[n * 128 + lane + 64];
    __syncthreads();
    for (int t = 0; t < 2; ++t) {
        int o = lane + 64 * t;
        const float* w = Wi0 + o * 128;
        float acc = 0.f;
        for (int c = 0; c < 128; ++c) acc += w[c] * xs[wid][c];
        f0[n * 128 + o] = acc;
    }
    if (lane < 32) {
        int c = lane;
        float w0 = Wi1[c * 3 + 0], w1 = Wi1[c * 3 + 1], w2 = Wi1[c * 3 + 2];
        for (int m = 0; m < 3; ++m) {
            float cav = coords[(n * 4 + 1) * 3 + m];
            float a0 = coords[(n * 4 + 0) * 3 + m] - cav;  // N
            float a1 = coords[(n * 4 + 2) * 3 + m] - cav;  // C
            float a2 = coords[(n * 4 + 3) * 3 + m] - cav;  // O
            f1[(n * 32 + c) * 3 + m] = w0 * a0 + w1 * a1 + w2 * a2;
        }
    }
}

// ---------------- fiber norm (+ optional q projection) (one wave per node) ----------------
__global__ __launch_bounds__(256) void fnorm_kernel(const float* __restrict__ f0,
                                                    const float* __restrict__ f1,
                                                    const float* __restrict__ g0,
                                                    const float* __restrict__ b0,
                                                    const float* __restrict__ g1,
                                                    const float* __restrict__ b1,
                                                    const float* __restrict__ Wq0,
                                                    const float* __restrict__ Wq1,
                                                    float* __restrict__ x0,
                                                    float* __restrict__ x1,
                                                    float* __restrict__ q0,
                                                    float* __restrict__ q1) {
    __shared__ float x0s[4][128];
    __shared__ float x1s[4][96];
    const int wid = threadIdx.x >> 6, lane = threadIdx.x & 63;
    const int n = blockIdx.x * 4 + wid;
    float va = f0[n * 128 + lane], vb = f0[n * 128 + lane + 64];
    float m = wsum64(va + vb) * (1.0f / 128.0f);
    float da = va - m, db = vb - m;
    float var = wsum64(da * da + db * db) * (1.0f / 128.0f);
    float rs = rsqrtf(var + 1e-5f);
    float xa = gelu_f(da * rs * g0[lane] + b0[lane]);
    float xb = gelu_f(db * rs * g0[lane + 64] + b0[lane + 64]);
    x0s[wid][lane] = xa; x0s[wid][lane + 64] = xb;
    x0[n * 128 + lane] = xa; x0[n * 128 + lane + 64] = xb;
    int c = lane & 31;
    float h0 = f1[(n * 32 + c) * 3 + 0], h1 = f1[(n * 32 + c) * 3 + 1], h2 = f1[(n * 32 + c) * 3 + 2];
    float n1 = sqrtf(h0 * h0 + h1 * h1 + h2 * h2);
    float ms = wsum64(n1) * (1.0f / 64.0f);
    float dd = n1 - ms;
    float vv = wsum64(dd * dd) * (1.0f / 64.0f);
    float sc = gelu_f(dd * rsqrtf(vv + 1e-5f) * g1[c] + b1[c]) / (n1 + 1e-6f);
    if (lane < 32) {
        float o0v = h0 * sc, o1v = h1 * sc, o2v = h2 * sc;
        x1s[wid][c * 3 + 0] = o0v; x1s[wid][c * 3 + 1] = o1v; x1s[wid][c * 3 + 2] = o2v;
        x1[(n * 32 + c) * 3 + 0] = o0v; x1[(n * 32 + c) * 3 + 1] = o1v; x1[(n * 32 + c) * 3 + 2] = o2v;
    }
    __syncthreads();
    if (Wq0 != nullptr) {
        for (int t = 0; t < 2; ++t) {
            int o = lane + 64 * t;
            const float* w = Wq0 + o * 128;
            float acc = 0.f;
            for (int cc = 0; cc < 128; ++cc) acc += w[cc] * x0s[wid][cc];
            q0[n * 128 + o] = acc;
        }
        for (int val = lane; val < 96; val += 64) {
            int o = val & 31, mm = val >> 5;
            const float* w = Wq1 + o * 32;
            float acc = 0.f;
            for (int cc = 0; cc < 32; ++cc) acc += w[cc] * x1s[wid][cc * 3 + mm];
            q1[(n * 32 + o) * 3 + mm] = acc;
        }
    }
}

// =====================================================================
//  Radial GEMM with fused TFN pointwise epilogue.
//  R[e][r] = sum_k edges[e][k] * Wr[r][k]   (E=16384, 384 rows, K=64)
//  Epilogue writes:
//    r in [0,128)  : in0[e][r]        = R * x0[j][r]
//    r in [128,160): in0[e][128+c]    = R * dot1[c]          (c=r-128)
//    r in [160,288): inU[e][c]        = R * x0[j][c]         (c=r-160)
//    r in [288,320): inW[m][e][c]     = R * x1[j][c][m]      (c=r-288)
//    r in [320,352): inW[m][e][32+c]  = R * cross(x1,y)[c][m]
//    r in [352,384): inW[m][e][64+c]  = R * (y[m]*dot1[c] - x1[j][c][m]/3)
// =====================================================================
__global__ __launch_bounds__(256) void radial_kernel(const float* __restrict__ edges,
                                                     const float* __restrict__ Wr,
                                                     const float* __restrict__ x0,
                                                     const float* __restrict__ x1,
                                                     const int* __restrict__ idx,
                                                     const float* __restrict__ y1,
                                                     float* __restrict__ in0,
                                                     float* __restrict__ inU,
                                                     float* __restrict__ inW) {
    constexpr int BM = 128, BN = 64, BK = 32, TM = 8, TN = 4;
    __shared__ float As[BK][BM + 8];
    __shared__ float Bs[BK][BN + 8];
    const int t = threadIdx.x;
    const int e0 = blockIdx.x * BM;
    const int r0 = blockIdx.y * BN;
    const int tm = (t >> 4) * TM;
    const int tn = (t & 15) * TN;
    float acc[TM][TN] = {};
    for (int kc = 0; kc < 64; kc += BK) {
#pragma unroll
        for (int i = 0; i < 4; ++i) {
            int f = t + 256 * i;
            int m = f >> 3, k4 = (f & 7) * 4;
            float4 a = *(const float4*)&edges[(size_t)(e0 + m) * 64 + kc + k4];
            As[k4 + 0][m] = a.x; As[k4 + 1][m] = a.y; As[k4 + 2][m] = a.z; As[k4 + 3][m] = a.w;
        }
#pragma unroll
        for (int i = 0; i < 2; ++i) {
            int f = t + 256 * i;
            int n = f >> 3, k4 = (f & 7) * 4;
            float4 b = *(const float4*)&Wr[(size_t)(r0 + n) * 64 + kc + k4];
            Bs[k4 + 0][n] = b.x; Bs[k4 + 1][n] = b.y; Bs[k4 + 2][n] = b.z; Bs[k4 + 3][n] = b.w;
        }
        __syncthreads();
#pragma unroll
        for (int k = 0; k < BK; ++k) {
            float a[TM], b[TN];
            *(float4*)&a[0] = *(const float4*)&As[k][tm];
            *(float4*)&a[4] = *(const float4*)&As[k][tm + 4];
            *(float4*)&b[0] = *(const float4*)&Bs[k][tn];
#pragma unroll
            for (int mm = 0; mm < TM; ++mm)
#pragma unroll
                for (int nn = 0; nn < TN; ++nn) acc[mm][nn] += a[mm] * b[nn];
        }
        __syncthreads();
    }
    const int r = r0 + tn;
#pragma unroll
    for (int mm = 0; mm < TM; ++mm) {
        const int e = e0 + tm + mm;
        const int j = idx[e];
        const float ya = y1[e * 3 + 0], yb = y1[e * 3 + 1], yc = y1[e * 3 + 2];
        if (r < 128) {
            const float4 xv = *(const float4*)&x0[j * 128 + r];
            float4 o;
            o.x = acc[mm][0] * xv.x; o.y = acc[mm][1] * xv.y;
            o.z = acc[mm][2] * xv.z; o.w = acc[mm][3] * xv.w;
            *(float4*)&in0[(size_t)e * 160 + r] = o;
        } else if (r < 160) {
            const int c = r - 128;
            float fx[12];
            *(float4*)&fx[0] = *(const float4*)&x1[j * 96 + c * 3];
            *(float4*)&fx[4] = *(const float4*)&x1[j * 96 + c * 3 + 4];
            *(float4*)&fx[8] = *(const float4*)&x1[j * 96 + c * 3 + 8];
            float4 o;
            float* op = &o.x;
#pragma unroll
            for (int nn = 0; nn < 4; ++nn) {
                float d = fx[nn * 3] * ya + fx[nn * 3 + 1] * yb + fx[nn * 3 + 2] * yc;
                op[nn] = acc[mm][nn] * d;
            }
            *(float4*)&in0[(size_t)e * 160 + 128 + c] = o;
        } else if (r < 288) {
            const int c = r - 160;
            const float4 xv = *(const float4*)&x0[j * 128 + c];
            float4 o;
            o.x = acc[mm][0] * xv.x; o.y = acc[mm][1] * xv.y;
            o.z = acc[mm][2] * xv.z; o.w = acc[mm][3] * xv.w;
            *(float4*)&inU[(size_t)e * 128 + c] = o;
        } else {
            const int c = (r < 320) ? (r - 288) : (r < 352) ? (r - 320) : (r - 352);
            float fx[12];
            *(float4*)&fx[0] = *(const float4*)&x1[j * 96 + c * 3];
            *(float4*)&fx[4] = *(const float4*)&x1[j * 96 + c * 3 + 4];
            *(float4*)&fx[8] = *(const float4*)&x1[j * 96 + c * 3 + 8];
            float w0[4], w1[4], w2[4];
            int off;
            if (r < 320) {
                off = 0;
#pragma unroll
                for (int nn = 0; nn < 4; ++nn) {
                    w0[nn] = acc[mm][nn] * fx[nn * 3 + 0];
                    w1[nn] = acc[mm][nn] * fx[nn * 3 + 1];
                    w2[nn] = acc[mm][nn] * fx[nn * 3 + 2];
                }
            } else if (r < 352) {
                off = 32;
#pragma unroll
                for (int nn = 0; nn < 4; ++nn) {
                    float fxv = fx[nn * 3 + 0], fyv = fx[nn * 3 + 1], fzv = fx[nn * 3 + 2];
                    w0[nn] = acc[mm][nn] * (fyv * yc - fzv * yb);
                    w1[nn] = acc[mm][nn] * (fzv * ya - fxv * yc);
                    w2[nn] = acc[mm][nn] * (fxv * yb - fyv * ya);
                }
            } else {
                off = 64;
#pragma unroll
                for (int nn = 0; nn < 4; ++nn) {
                    float fxv = fx[nn * 3 + 0], fyv = fx[nn * 3 + 1], fzv = fx[nn * 3 + 2];
                    float d = fxv * ya + fyv * yb + fzv * yc;
                    w0[nn] = acc[mm][nn] * (ya * d - fxv * (1.0f / 3.0f));
                    w1[nn] = acc[mm][nn] * (yb * d - fyv * (1.0f / 3.0f));
                    w2[nn] = acc[mm][nn] * (yc * d - fzv * (1.0f / 3.0f));
                }
            }
            *(float4*)&inW[((size_t)0 * ENUM + e) * 96 + off + c] = make_float4(w0[0], w0[1], w0[2], w0[3]);
            *(float4*)&inW[((size_t)1 * ENUM + e) * 96 + off + c] = make_float4(w1[0], w1[1], w1[2], w1[3]);
            *(float4*)&inW[((size_t)2 * ENUM + e) * 96 + off + c] = make_float4(w2[0], w2[1], w2[2], w2[3]);
        }
    }
}

// =====================================================================
//  Generic tiled f32 GEMM: C[M,N] = A[M,K] @ B[N,K]^T  (all row-major)
//  BM=128, BK=32, TM=8.  EPI: 0 = plain store, 1 = k1 rank-1 add
//  (C[row][n] = acc + U[e][n]*Y[e][m], row = m*16384 + e).
// =====================================================================
template <int BN, int TN, int EPI>
__global__ __launch_bounds__(256) void gemm_nt(const float* __restrict__ A,
                                               const float* __restrict__ B,
                                               float* __restrict__ C,
                                               int K, int lda, int ldb, int ldc,
                                               const float* __restrict__ U,
                                               const float* __restrict__ Y) {
    constexpr int BM = 128, BK = 32, TM = 8;
    __shared__ float As[BK][BM + 8];
    __shared__ float Bs[BK][BN + 8];
    const int t = threadIdx.x;
    const int m0 = blockIdx.x * BM;
    const int n0 = blockIdx.y * BN;
    const int tm = (t / (BN / TN)) * TM;
    const int tn = (t % (BN / TN)) * TN;
    float acc[TM][TN] = {};
    for (int kc = 0; kc < K; kc += BK) {
#pragma unroll
        for (int i = 0; i < 4; ++i) {
            int f = t + 256 * i;
            int m = f >> 3, k4 = (f & 7) * 4;
            float4 a = *(const float4*)&A[(size_t)(m0 + m) * lda + kc + k4];
            As[k4 + 0][m] = a.x; As[k4 + 1][m] = a.y; As[k4 + 2][m] = a.z; As[k4 + 3][m] = a.w;
        }
#pragma unroll
        for (int i = 0; i < (BN * BK) / 1024; ++i) {
            int f = t + 256 * i;
            int n = f >> 3, k4 = (f & 7) * 4;
            float4 b = *(const float4*)&B[(size_t)(n0 + n) * ldb + kc + k4];
            Bs[k4 + 0][n] = b.x; Bs[k4 + 1][n] = b.y; Bs[k4 + 2][n] = b.z; Bs[k4 + 3][n] = b.w;
        }
        __syncthreads();
#pragma unroll
        for (int k = 0; k < BK; ++k) {
            float a[TM], b[TN];
            *(float4*)&a[0] = *(const float4*)&As[k][tm];
            *(float4*)&a[4] = *(const float4*)&As[k][tm + 4];
            if (TN == 4) {
                *(float4*)&b[0] = *(const float4*)&Bs[k][tn];
            } else {
                *(float2*)&b[0] = *(const float2*)&Bs[k][tn];
            }
#pragma unroll
            for (int mm = 0; mm < TM; ++mm)
#pragma unroll
                for (int nn = 0; nn < TN; ++nn) acc[mm][nn] += a[mm] * b[nn];
        }
        __syncthreads();
    }
#pragma unroll
    for (int mm = 0; mm < TM; ++mm) {
        const int row = m0 + tm + mm;
        if (EPI == 1) {
            const int m = row >> 14, e = row & 16383;
            const float yv = Y[e * 3 + m];
            const float2 uv = *(const float2*)&U[e * 32 + n0 + tn];
            float2 o;
            o.x = acc[mm][0] + uv.x * yv;
            o.y = acc[mm][1] + uv.y * yv;
            *(float2*)&C[(size_t)row * ldc + n0 + tn] = o;
        } else if (TN == 4) {
            *(float4*)&C[(size_t)row * ldc + n0 + tn] =
                make_float4(acc[mm][0], acc[mm][1], acc[mm][2], acc[mm][3]);
        } else {
            *(float2*)&C[(size_t)row * ldc + n0 + tn] = make_float2(acc[mm][0], acc[mm][1]);
        }
    }
}

// ---------------- OLD TFN kernel (workspace-size fallback only) ----------------
__global__ __launch_bounds__(256) void tfn_kernel(const float* __restrict__ edges,
                                                  const float* __restrict__ x0,
                                                  const float* __restrict__ x1,
                                                  const int* __restrict__ idx,
                                                  const float* __restrict__ y1,
                                                  const float* __restrict__ Wr,
                                                  const float* __restrict__ WA,
                                                  const float* __restrict__ WB,
                                                  float* __restrict__ k0,
                                                  float* __restrict__ k1) {
    __shared__ float es[4][64];
    __shared__ float x0js[4][128];
    __shared__ float x1js[4][96];
    __shared__ float dot1s[4][32];
    __shared__ float in0s[4][160];
    __shared__ float in1s[4][672];
    const int wid = threadIdx.x >> 6, lane = threadIdx.x & 63;
    const int e = blockIdx.x * 4 + wid;
    const int j = idx[e];
    es[wid][lane] = edges[e * 64 + lane];
    x0js[wid][lane]      = x0[j * 128 + lane];
    x0js[wid][lane + 64] = x0[j * 128 + lane + 64];
    if (lane < 32) {
        x1js[wid][lane * 3 + 0] = x1[(j * 32 + lane) * 3 + 0];
        x1js[wid][lane * 3 + 1] = x1[(j * 32 + lane) * 3 + 1];
        x1js[wid][lane * 3 + 2] = x1[(j * 32 + lane) * 3 + 2];
    }
    const float ya = y1[e * 3 + 0], yb = y1[e * 3 + 1], yc = y1[e * 3 + 2];
    __syncthreads();
    if (lane < 32) {
        dot1s[wid][lane] = x1js[wid][lane * 3 + 0] * ya + x1js[wid][lane * 3 + 1] * yb
                         + x1js[wid][lane * 3 + 2] * yc;
    }
    __syncthreads();
    for (int t = 0; t < 6; ++t) {
        int row = lane + 64 * t;
        const float* w = Wr + row * 64;
        float acc = 0.f;
        for (int i = 0; i < 64; ++i) acc += w[i] * es[wid][i];
        if (row < 128) {
            in0s[wid][row] = acc * x0js[wid][row];
        } else if (row < 160) {
            int c = row - 128;
            in0s[wid][128 + c] = acc * dot1s[wid][c];
        } else if (row < 288) {
            int c = row - 160;
            float f = acc * x0js[wid][c];
            in1s[wid][c * 3 + 0] = f * ya; in1s[wid][c * 3 + 1] = f * yb; in1s[wid][c * 3 + 2] = f * yc;
        } else if (row < 320) {
            int c = row - 288;
            in1s[wid][(128 + c) * 3 + 0] = acc * x1js[wid][c * 3 + 0];
            in1s[wid][(128 + c) * 3 + 1] = acc * x1js[wid][c * 3 + 1];
            in1s[wid][(128 + c) * 3 + 2] = acc * x1js[wid][c * 3 + 2];
        } else if (row < 352) {
            int c = row - 320;
            float fx = x1js[wid][c * 3 + 0], fy = x1js[wid][c * 3 + 1], fz = x1js[wid][c * 3 + 2];
            in1s[wid][(160 + c) * 3 + 0] = acc * (fy * yc - fz * yb);
            in1s[wid][(160 + c) * 3 + 1] = acc * (fz * ya - fx * yc);
            in1s[wid][(160 + c) * 3 + 2] = acc * (fx * yb - fy * ya);
        } else {
            int c = row - 352;
            float d = dot1s[wid][c];
            in1s[wid][(192 + c) * 3 + 0] = acc * (ya * d - x1js[wid][c * 3 + 0] * (1.0f / 3.0f));
            in1s[wid][(192 + c) * 3 + 1] = acc * (yb * d - x1js[wid][c * 3 + 1] * (1.0f / 3.0f));
            in1s[wid][(192 + c) * 3 + 2] = acc * (yc * d - x1js[wid][c * 3 + 2] * (1.0f / 3.0f));
        }
    }
    __syncthreads();
    for (int t = 0; t < 2; ++t) {
        int o = lane + 64 * t;
        const float* w = WA + o * 160;
        float acc = 0.f;
        for (int c = 0; c < 160; ++c) acc += w[c] * in0s[wid][c];
        k0[e * 128 + o] = acc;
    }
    for (int val = lane; val < 96; val += 64) {
        int o = val & 31, m = val >> 5;
        const float* w = WB + o * 224;
        float acc = 0.f;
        for (int c = 0; c < 224; ++c) acc += w[c] * in1s[wid][c * 3 + m];
        k1[(e * 32 + o) * 3 + m] = acc;
    }
}

// ---------------- attention + output projection + residual (one wave per node) ----------------
// NEWL: k1/v1 in [3][E][32] layout; else old [(e*32+c)*3+m].
template <bool NEWL>
__global__ __launch_bounds__(256) void attn_kernel(const float* __restrict__ q0,
                                                   const float* __restrict__ q1,
                                                   const float* __restrict__ k0,
                                                   const float* __restrict__ k1,
                                                   const float* __restrict__ v0,
                                                   const float* __restrict__ v1,
                                                   const float* __restrict__ edges,
                                                   const float* __restrict__ maskf,
                                                   const float* __restrict__ Wb,
                                                   const float* __restrict__ Wo0,
                                                   const float* __restrict__ Wo1,
                                                   const float* __restrict__ alpha,
                                                   float* __restrict__ f0,
                                                   float* __restrict__ f1) {
    __shared__ float q0s[4][128];
    __shared__ float q1s[4][96];
    __shared__ float attns[4][64];
    __shared__ float o0s[4][128];
    __shared__ float o1s[4][96];
    const int wid = threadIdx.x >> 6, lane = threadIdx.x & 63;
    const int n = blockIdx.x * 4 + wid;
    q0s[wid][lane]      = q0[n * 128 + lane];
    q0s[wid][lane + 64] = q0[n * 128 + lane + 64];
    if (lane < 32) {
        q1s[wid][lane * 3 + 0] = q1[(n * 32 + lane) * 3 + 0];
        q1s[wid][lane * 3 + 1] = q1[(n * 32 + lane) * 3 + 1];
        q1s[wid][lane * 3 + 2] = q1[(n * 32 + lane) * 3 + 2];
    }
    __syncthreads();
    const int h = lane >> 4, k = lane & 15;
    const int e = n * KK + k;
    float acc = 0.f;
    for (int c = 0; c < 32; ++c) acc += q0s[wid][h * 32 + c] * k0[e * 128 + h * 32 + c];
    if (NEWL) {
        for (int m = 0; m < 3; ++m)
            for (int c = 0; c < 8; ++c)
                acc += q1s[wid][(h * 8 + c) * 3 + m] * k1[((size_t)m * ENUM + e) * 32 + h * 8 + c];
    } else {
        for (int c = 0; c < 8; ++c)
            for (int m = 0; m < 3; ++m)
                acc += q1s[wid][(h * 8 + c) * 3 + m] * k1[(e * 32 + h * 8 + c) * 3 + m];
    }
    acc *= SCALE_ATTN;
    float bias = 0.f;
    for (int i = 0; i < 64; ++i) bias += Wb[h * 64 + i] * edges[e * 64 + i];
    acc += bias;
    if (maskf[e] == 0.0f) acc = -1e9f;
    float mx = gmax16(acc);
    float ex = expf(acc - mx);
    float sm = gsum16(ex);
    attns[wid][lane] = ex / sm;
    __syncthreads();
    for (int t = 0; t < 2; ++t) {
        int oc = lane + 64 * t;
        int h2 = oc >> 5;
        float a = 0.f;
        for (int kk = 0; kk < KK; ++kk) a += attns[wid][h2 * 16 + kk] * v0[(n * KK + kk) * 128 + oc];
        o0s[wid][oc] = a;
    }
    for (int val = lane; val < 96; val += 64) {
        int cc = val & 31, m = val >> 5;
        int h2 = cc >> 3;
        float a = 0.f;
        if (NEWL) {
            for (int kk = 0; kk < KK; ++kk)
                a += attns[wid][h2 * 16 + kk] * v1[((size_t)m * ENUM + n * KK + kk) * 32 + cc];
        } else {
            for (int kk = 0; kk < KK; ++kk)
                a += attns[wid][h2 * 16 + kk] * v1[((n * KK + kk) * 32 + cc) * 3 + m];
        }
        o1s[wid][cc * 3 + m] = a;
    }
    __syncthreads();
    const float al = alpha[0];
    for (int t = 0; t < 2; ++t) {
        int o = lane + 64 * t;
        const float* w = Wo0 + o * 128;
        float a = 0.f;
        for (int c = 0; c < 128; ++c) a += w[c] * o0s[wid][c];
        f0[n * 128 + o] += al * a;
    }
    for (int val = lane; val < 96; val += 64) {
        int o = val & 31, m = val >> 5;
        const float* w = Wo1 + o * 32;
        float a = 0.f;
        for (int c = 0; c < 32; ++c) a += w[c] * o1s[wid][c * 3 + m];
        f1[(n * 32 + o) * 3 + m] += al * a;
    }
}

// ---------------- fiber feed-forward + residual (one wave per node) ----------------
__global__ __launch_bounds__(256) void ff_kernel(const float* __restrict__ x0,
                                                 const float* __restrict__ x1,
                                                 const float* __restrict__ Wf0a,
                                                 const float* __restrict__ Wf0b,
                                                 const float* __restrict__ Wf1a,
                                                 const float* __restrict__ Wf1b,
                                                 const float* __restrict__ alpha,
                                                 float* __restrict__ f0,
                                                 float* __restrict__ f1) {
    __shared__ float x0s[4][128];
    __shared__ float hs[4][512];
    __shared__ float x1s[4][96];
    __shared__ float h1s[4][384];
    const int wid = threadIdx.x >> 6, lane = threadIdx.x & 63;
    const int n = blockIdx.x * 4 + wid;
    x0s[wid][lane]      = x0[n * 128 + lane];
    x0s[wid][lane + 64] = x0[n * 128 + lane + 64];
    if (lane < 32) {
        x1s[wid][lane * 3 + 0] = x1[(n * 32 + lane) * 3 + 0];
        x1s[wid][lane * 3 + 1] = x1[(n * 32 + lane) * 3 + 1];
        x1s[wid][lane * 3 + 2] = x1[(n * 32 + lane) * 3 + 2];
    }
    __syncthreads();
    for (int t = 0; t < 8; ++t) {
        int r = lane + 64 * t;
        const float* w = Wf0a + r * 128;
        float a = 0.f;
        for (int c = 0; c < 128; ++c) a += w[c] * x0s[wid][c];
        hs[wid][r] = gelu_f(a);
    }
    for (int t = 0; t < 2; ++t) {
        int r = lane + 64 * t;
        const float* w = Wf1a + r * 32;
        float t0 = 0.f, t1 = 0.f, t2 = 0.f;
        for (int c = 0; c < 32; ++c) {
            float wv = w[c];
            t0 += wv * x1s[wid][c * 3 + 0];
            t1 += wv * x1s[wid][c * 3 + 1];
            t2 += wv * x1s[wid][c * 3 + 2];
        }
        float nh = sqrtf(t0 * t0 + t1 * t1 + t2 * t2);
        float sc = gelu_f(nh) / (nh + 1e-6f);
        h1s[wid][r * 3 + 0] = t0 * sc; h1s[wid][r * 3 + 1] = t1 * sc; h1s[wid][r * 3 + 2] = t2 * sc;
    }
    __syncthreads();
    const float al = alpha[0];
    for (int t = 0; t < 2; ++t) {
        int o = lane + 64 * t;
        const float* w = Wf0b + o * 512;
        float a = 0.f;
        for (int r = 0; r < 512; ++r) a += w[r] * hs[wid][r];
        f0[n * 128 + o] += al * a;
    }
    for (int val = lane; val < 96; val += 64) {
        int o = val & 31, m = val >> 5;
        const float* w = Wf1b + o * 128;
        float a = 0.f;
        for (int r = 0; r < 128; ++r) a += w[r] * h1s[wid][r * 3 + m];
        f1[(n * 32 + o) * 3 + m] += al * a;
    }
}

// ---------------- output projection (one wave per node) ----------------
__global__ __launch_bounds__(256) void out_kernel(const float* __restrict__ f0,
                                                  const float* __restrict__ f1,
                                                  const float* __restrict__ coords,
                                                  const float* __restrict__ Wp0,
                                                  const float* __restrict__ Wp1,
                                                  float* __restrict__ out) {
    __shared__ float f0s[4][128];
    const int wid = threadIdx.x >> 6, lane = threadIdx.x & 63;
    const int n = blockIdx.x * 4 + wid;
    f0s[wid][lane]      = f0[n * 128 + lane];
    f0s[wid][lane + 64] = f0[n * 128 + lane + 64];
    __syncthreads();
    for (int t = 0; t < 2; ++t) {
        int o = lane + 64 * t;
        const float* w = Wp0 + o * 128;
        float a = 0.f;
        for (int c = 0; c < 128; ++c) a += w[c] * f0s[wid][c];
        out[n * 128 + o] = a;
    }
    if (lane < 9) {
        int o = lane / 3, m = lane % 3;
        float a = coords[(n * 4 + 1) * 3 + m];
        const float* w = Wp1 + o * 32;
        for (int c = 0; c < 32; ++c) a += w[c] * f1[(n * 32 + c) * 3 + m];
        out[NN * 128 + (n * 3 + o) * 3 + m] = a;
    }
}

extern "C" void kernel_launch(void* const* d_in, const int* in_sizes, int n_in,
                              void* d_out, int out_size, void* d_ws, size_t ws_size,
                              hipStream_t stream) {
    (void)in_sizes; (void)n_in; (void)out_size;
    const float* node_feats = (const float*)d_in[0];
    const float* pair       = (const float*)d_in[1];
    const float* coords     = (const float*)d_in[2];
    const float* eln_g      = (const float*)d_in[3];
    const float* eln_b      = (const float*)d_in[4];
    const float* Wi0        = (const float*)d_in[5];
    const float* Wi1        = (const float*)d_in[6];
    const float* ln0_g      = (const float*)d_in[7];
    const float* ln0_b      = (const float*)d_in[8];
    const float* n1_g       = (const float*)d_in[9];
    const float* n1_b       = (const float*)d_in[10];
    const float* Wq0        = (const float*)d_in[11];
    const float* Wq1        = (const float*)d_in[12];
    const float* WrK        = (const float*)d_in[13];
    const float* WrV        = (const float*)d_in[14];
    const float* WkA        = (const float*)d_in[15];
    const float* WkB        = (const float*)d_in[16];
    const float* WvA        = (const float*)d_in[17];
    const float* WvB        = (const float*)d_in[18];
    const float* Wb         = (const float*)d_in[19];
    const float* Wo0        = (const float*)d_in[20];
    const float* Wo1        = (const float*)d_in[21];
    const float* alpha_attn = (const float*)d_in[22];
    const float* lnf0_g     = (const float*)d_in[23];
    const float* lnf0_b     = (const float*)d_in[24];
    const float* nf1_g      = (const float*)d_in[25];
    const float* nf1_b      = (const float*)d_in[26];
    const float* Wf0a       = (const float*)d_in[27];
    const float* Wf0b       = (const float*)d_in[28];
    const float* Wf1a       = (const float*)d_in[29];
    const float* Wf1b       = (const float*)d_in[30];
    const float* alpha_ff   = (const float*)d_in[31];
    const float* Wp0        = (const float*)d_in[32];
    const float* Wp1        = (const float*)d_in[33];
    float* out = (float*)d_out;

    float* ws = (float*)d_ws;
    size_t off = 0;
    int*   idx   = (int*)(ws + off); off += NN * KK;
    float* maskf = ws + off;         off += NN * KK;
    float* y1    = ws + off;         off += NN * KK * 3;
    float* edges = ws + off;         off += (size_t)ENUM * EDc;
    float* f0    = ws + off;         off += NN * C0c;
    float* f1    = ws + off;         off += NN * C1c * 3;
    float* x0    = ws + off;         off += NN * C0c;
    float* x1    = ws + off;         off += NN * C1c * 3;
    float* q0    = ws + off;         off += NN * C0c;
    float* q1    = ws + off;         off += NN * C1c * 3;
    float* k0    = ws + off;         off += (size_t)ENUM * C0c;
    float* k1    = ws + off;         off += (size_t)ENUM * C1c * 3;
    float* v0    = ws + off;         off += (size_t)ENUM * C0c;
    float* v1    = ws + off;         off += (size_t)ENUM * C1c * 3;
    float* in0   = ws + off;         off += (size_t)ENUM * 160;
    float* inU   = ws + off;         off += (size_t)ENUM * 128;
    float* inW   = ws + off;         off += (size_t)ENUM * 96 * 3;
    float* u     = ws + off;         off += (size_t)ENUM * 32;
    const bool fast = ws_size >= off * sizeof(float);

    knn_kernel<<<NN, 256, 0, stream>>>(coords, idx, maskf, y1);
    edge_ln_kernel<<<ENUM / 4, 256, 0, stream>>>(pair, idx, eln_g, eln_b, edges);
    init_kernel<<<NN / 4, 256, 0, stream>>>(node_feats, coords, Wi0, Wi1, f0, f1);

    for (int l = 0; l < Lc; ++l) {
        fnorm_kernel<<<NN / 4, 256, 0, stream>>>(f0, f1,
            ln0_g + l * 128, ln0_b + l * 128, n1_g + l * 32, n1_b + l * 32,
            Wq0 + l * 128 * 128, Wq1 + l * 32 * 32, x0, x1, q0, q1);
        if (fast) {
            const float* WrL[2] = {WrK + (size_t)l * 384 * 64, WrV + (size_t)l * 384 * 64};
            const float* WAL[2] = {WkA + (size_t)l * 128 * 160, WvA + (size_t)l * 128 * 160};
            const float* WBL[2] = {WkB + (size_t)l * 32 * 224, WvB + (size_t)l * 32 * 224};
            float* O0[2] = {k0, v0};
            float* O1[2] = {k1, v1};
            for (int s = 0; s < 2; ++s) {
                radial_kernel<<<dim3(ENUM / 128, 6), 256, 0, stream>>>(
                    edges, WrL[s], x0, x1, idx, y1, in0, inU, inW);
                gemm_nt<64, 4, 0><<<dim3(ENUM / 128, 2), 256, 0, stream>>>(
                    in0, WAL[s], O0[s], 160, 160, 160, 128, nullptr, nullptr);
                gemm_nt<32, 2, 0><<<dim3(ENUM / 128, 1), 256, 0, stream>>>(
                    inU, WBL[s], u, 128, 128, 224, 32, nullptr, nullptr);
                gemm_nt<32, 2, 1><<<dim3(3 * ENUM / 128, 1), 256, 0, stream>>>(
                    inW, WBL[s] + 128, O1[s], 96, 96, 224, 32, u, y1);
            }
            attn_kernel<true><<<NN / 4, 256, 0, stream>>>(q0, q1, k0, k1, v0, v1, edges, maskf,
                Wb + l * Hc * 64, Wo0 + l * 128 * 128, Wo1 + l * 32 * 32,
                alpha_attn + l, f0, f1);
        } else {
            tfn_kernel<<<ENUM / 4, 256, 0, stream>>>(edges, x0, x1, idx, y1,
                WrK + (size_t)l * 384 * 64, WkA + (size_t)l * 128 * 160,
                WkB + (size_t)l * 32 * 224, k0, k1);
            tfn_kernel<<<ENUM / 4, 256, 0, stream>>>(edges, x0, x1, idx, y1,
                WrV + (size_t)l * 384 * 64, WvA + (size_t)l * 128 * 160,
                WvB + (size_t)l * 32 * 224, v0, v1);
            attn_kernel<false><<<NN / 4, 256, 0, stream>>>(q0, q1, k0, k1, v0, v1, edges, maskf,
                Wb + l * Hc * 64, Wo0 + l * 128 * 128, Wo1 + l * 32 * 32,
                alpha_attn + l, f0, f1);
        }
        fnorm_kernel<<<NN / 4, 256, 0, stream>>>(f0, f1,
            lnf0_g + l * 128, lnf0_b + l * 128, nf1_g + l * 32, nf1_b + l * 32,
            nullptr, nullptr, x0, x1, nullptr, nullptr);
        ff_kernel<<<NN / 4, 256, 0, stream>>>(x0, x1,
            Wf0a + (size_t)l * 512 * 128, Wf0b + (size_t)l * 128 * 512,
            Wf1a + (size_t)l * 128 * 32, Wf1b + (size_t)l * 32 * 128,
            alpha_ff + l, f0, f1);
    }

    out_kernel<<<NN / 4, 256, 0, stream>>>(f0, f1, coords, Wp0, Wp1, out);
}

// Round 3
// 507.163 us; speedup vs baseline: 4.2129x; 1.0011x over previous
//
#include <hip/hip_runtime.h>
#include <hip/hip_bf16.h>
#include <math.h>

// ---- problem constants ----
static constexpr int NN  = 1024;
static constexpr int KK  = 16;
static constexpr int C0c = 128;
static constexpr int C1c = 32;
static constexpr int EDc = 64;
static constexpr int Hc  = 4;
static constexpr int Lc  = 2;
static constexpr int ENUM = NN * KK;        // 16384 edges
static constexpr int PL   = NN * C1c;       // 32768: m-plane stride (node tensors)
static constexpr int HPL  = NN * 128;       // 131072: m-plane stride for h1t
#define SCALE_ATTN 0.13363062095621219f     /* 1/sqrt(32+3*8) */

__device__ __forceinline__ float wsum64(float v) {
    for (int o = 32; o > 0; o >>= 1) v += __shfl_xor(v, o);
    return v;
}
__device__ __forceinline__ float gsum16(float v) {
    for (int o = 8; o > 0; o >>= 1) v += __shfl_xor(v, o, 16);
    return v;
}
__device__ __forceinline__ float gmax16(float v) {
    for (int o = 8; o > 0; o >>= 1) v = fmaxf(v, __shfl_xor(v, o, 16));
    return v;
}
__device__ __forceinline__ float gelu_f(float x) {
    float x3 = x * x * x;
    return 0.5f * x * (1.0f + tanhf(0.7978845608028654f * (x + 0.044715f * x3)));
}

// ---------------- kNN: wave per node, register distances ----------------
__global__ __launch_bounds__(256) void knn_kernel2(const float* __restrict__ coords,
                                                   int* __restrict__ idx,
                                                   float* __restrict__ maskf,
                                                   float* __restrict__ y1) {
    __shared__ float ca[NN * 3];
    const int tid = threadIdx.x;
    for (int f = tid; f < NN * 3; f += 256) {
        int i = f / 3, m = f % 3;
        ca[f] = coords[(i * 4 + 1) * 3 + m];
    }
    __syncthreads();
    const int wid = tid >> 6, lane = tid & 63;
    const int n = blockIdx.x * 4 + wid;
    const float cx = ca[n * 3 + 0], cy = ca[n * 3 + 1], cz = ca[n * 3 + 2];
    float d[16];
#pragma unroll
    for (int s = 0; s < 16; ++s) {
        int i = s * 64 + lane;
        float dx = cx - ca[i * 3 + 0], dy = cy - ca[i * 3 + 1], dz = cz - ca[i * 3 + 2];
        float d2 = dx * dx + dy * dy + dz * dz;
        d[s] = (i == n) ? 1e9f : d2;
    }
    for (int t = 0; t < KK; ++t) {
        float best = 1e30f; int bi = 0;
#pragma unroll
        for (int s = 0; s < 16; ++s) {
            int i = s * 64 + lane;
            float v = d[s];
            if (v < best || (v == best && i < bi)) { best = v; bi = i; }
        }
#pragma unroll
        for (int o = 32; o > 0; o >>= 1) {
            float ov = __shfl_xor(best, o);
            int   oi = __shfl_xor(bi, o);
            if (ov < best || (ov == best && oi < bi)) { best = ov; bi = oi; }
        }
        const int j = bi;
        if (lane == 0) {
            idx[n * KK + t] = j;
            float dist = sqrtf(best);
            maskf[n * KK + t] = (dist <= 16.0f) ? 1.0f : 0.0f;
            float rx = ca[j * 3 + 0] - cx, ry = ca[j * 3 + 1] - cy, rz = ca[j * 3 + 2] - cz;
            float nrm = sqrtf(rx * rx + ry * ry + rz * rz) + 1e-6f;
            y1[(n * KK + t) * 3 + 0] = rx / nrm;
            y1[(n * KK + t) * 3 + 1] = ry / nrm;
            y1[(n * KK + t) * 3 + 2] = rz / nrm;
        }
        const int js = j >> 6, jl = j & 63;
#pragma unroll
        for (int s = 0; s < 16; ++s)
            if (s == js && jl == lane) d[s] = 2e30f;
    }
}

// ---------------- edge gather + LayerNorm (one wave per edge) ----------------
__global__ __launch_bounds__(256) void edge_ln_kernel(const float* __restrict__ pair,
                                                      const int* __restrict__ idx,
                                                      const float* __restrict__ g,
                                                      const float* __restrict__ b,
                                                      float* __restrict__ edges) {
    const int wid = threadIdx.x >> 6, lane = threadIdx.x & 63;
    const int e = blockIdx.x * 4 + wid;
    const int n = e >> 4;
    const int j = idx[e];
    float v = pair[((size_t)n * NN + j) * EDc + lane];
    float m = wsum64(v) * (1.0f / 64.0f);
    float d = v - m;
    float var = wsum64(d * d) * (1.0f / 64.0f);
    edges[e * EDc + lane] = d * rsqrtf(var + 1e-5f) * g[lane] + b[lane];
}

// ---------------- f1 input projection (planes) ----------------
__global__ __launch_bounds__(256) void f1init_kernel(const float* __restrict__ coords,
                                                     const float* __restrict__ Wi1,
                                                     float* __restrict__ f1p) {
    int g = blockIdx.x * 256 + threadIdx.x;
    if (g >= NN * 32) return;
    int n = g >> 5, c = g & 31;
    float w0 = Wi1[c * 3 + 0], w1 = Wi1[c * 3 + 1], w2 = Wi1[c * 3 + 2];
#pragma unroll
    for (int m = 0; m < 3; ++m) {
        float cav = coords[(n * 4 + 1) * 3 + m];
        float a0 = coords[(n * 4 + 0) * 3 + m] - cav;
        float a1 = coords[(n * 4 + 2) * 3 + m] - cav;
        float a2 = coords[(n * 4 + 3) * 3 + m] - cav;
        f1p[m * PL + n * 32 + c] = w0 * a0 + w1 * a1 + w2 * a2;
    }
}

// ---------------- fiber norm (one wave per node) ----------------
__global__ __launch_bounds__(256) void fnorm_kernel(const float* __restrict__ f0,
                                                    const float* __restrict__ f1p,
                                                    const float* __restrict__ g0,
                                                    const float* __restrict__ b0,
                                                    const float* __restrict__ g1,
                                                    const float* __restrict__ b1,
                                                    float* __restrict__ x0,
                                                    float* __restrict__ x1p) {
    const int wid = threadIdx.x >> 6, lane = threadIdx.x & 63;
    const int n = blockIdx.x * 4 + wid;
    float va = f0[n * 128 + lane], vb = f0[n * 128 + lane + 64];
    float m = wsum64(va + vb) * (1.0f / 128.0f);
    float da = va - m, db = vb - m;
    float var = wsum64(da * da + db * db) * (1.0f / 128.0f);
    float rs = rsqrtf(var + 1e-5f);
    x0[n * 128 + lane]      = gelu_f(da * rs * g0[lane] + b0[lane]);
    x0[n * 128 + lane + 64] = gelu_f(db * rs * g0[lane + 64] + b0[lane + 64]);
    int c = lane & 31;
    float h0 = f1p[0 * PL + n * 32 + c];
    float h1 = f1p[1 * PL + n * 32 + c];
    float h2 = f1p[2 * PL + n * 32 + c];
    float n1 = sqrtf(h0 * h0 + h1 * h1 + h2 * h2);
    float ms = wsum64(n1) * (1.0f / 64.0f);
    float dd = n1 - ms;
    float vv = wsum64(dd * dd) * (1.0f / 64.0f);
    float sc = gelu_f(dd * rsqrtf(vv + 1e-5f) * g1[c] + b1[c]) / (n1 + 1e-6f);
    if (lane < 32) {
        x1p[0 * PL + n * 32 + c] = h0 * sc;
        x1p[1 * PL + n * 32 + c] = h1 * sc;
        x1p[2 * PL + n * 32 + c] = h2 * sc;
    }
}

// =====================================================================
//  Radial GEMM (K & V batched on blockIdx.z) with TFN pointwise epilogue.
// =====================================================================
__global__ __launch_bounds__(256) void radial_kv(const float* __restrict__ edges,
                                                 const float* __restrict__ WrKl,
                                                 const float* __restrict__ WrVl,
                                                 const float* __restrict__ x0,
                                                 const float* __restrict__ x1p,
                                                 const int* __restrict__ idx,
                                                 const float* __restrict__ y1,
                                                 float* __restrict__ in0,
                                                 float* __restrict__ inU,
                                                 float* __restrict__ inW) {
    constexpr int BM = 128, BN = 64, BK = 32, TM = 8, TN = 4;
    __shared__ float As[BK][BM + 8];
    __shared__ float Bs[BK][BN + 8];
    const int t = threadIdx.x;
    const int s = blockIdx.z;
    const float* Wr = s ? WrVl : WrKl;
    float* in0s = in0 + (size_t)s * ENUM * 160;
    float* inUs = inU + (size_t)s * ENUM * 128;
    float* inWs = inW + (size_t)s * 3 * ENUM * 96;
    const int e0 = blockIdx.x * BM;
    const int r0 = blockIdx.y * BN;
    const int tm = (t >> 4) * TM;
    const int tn = (t & 15) * TN;
    float acc[TM][TN] = {};
    for (int kc = 0; kc < 64; kc += BK) {
#pragma unroll
        for (int i = 0; i < 4; ++i) {
            int f = t + 256 * i;
            int m = f >> 3, k4 = (f & 7) * 4;
            float4 a = *(const float4*)&edges[(size_t)(e0 + m) * 64 + kc + k4];
            As[k4 + 0][m] = a.x; As[k4 + 1][m] = a.y; As[k4 + 2][m] = a.z; As[k4 + 3][m] = a.w;
        }
#pragma unroll
        for (int i = 0; i < 2; ++i) {
            int f = t + 256 * i;
            int n = f >> 3, k4 = (f & 7) * 4;
            float4 b = *(const float4*)&Wr[(size_t)(r0 + n) * 64 + kc + k4];
            Bs[k4 + 0][n] = b.x; Bs[k4 + 1][n] = b.y; Bs[k4 + 2][n] = b.z; Bs[k4 + 3][n] = b.w;
        }
        __syncthreads();
#pragma unroll
        for (int k = 0; k < BK; ++k) {
            float a[TM], b[TN];
            *(float4*)&a[0] = *(const float4*)&As[k][tm];
            *(float4*)&a[4] = *(const float4*)&As[k][tm + 4];
            *(float4*)&b[0] = *(const float4*)&Bs[k][tn];
#pragma unroll
            for (int mm = 0; mm < TM; ++mm)
#pragma unroll
                for (int nn = 0; nn < TN; ++nn) acc[mm][nn] += a[mm] * b[nn];
        }
        __syncthreads();
    }
    const int r = r0 + tn;
#pragma unroll
    for (int mm = 0; mm < TM; ++mm) {
        const int e = e0 + tm + mm;
        const int j = idx[e];
        const float ya = y1[e * 3 + 0], yb = y1[e * 3 + 1], yc = y1[e * 3 + 2];
        if (r < 128) {
            const float4 xv = *(const float4*)&x0[j * 128 + r];
            float4 o;
            o.x = acc[mm][0] * xv.x; o.y = acc[mm][1] * xv.y;
            o.z = acc[mm][2] * xv.z; o.w = acc[mm][3] * xv.w;
            *(float4*)&in0s[(size_t)e * 160 + r] = o;
        } else if (r < 160) {
            const int c = r - 128;
            float4 p0 = *(const float4*)&x1p[0 * PL + j * 32 + c];
            float4 p1 = *(const float4*)&x1p[1 * PL + j * 32 + c];
            float4 p2 = *(const float4*)&x1p[2 * PL + j * 32 + c];
            const float* f0v = &p0.x; const float* f1v = &p1.x; const float* f2v = &p2.x;
            float4 o; float* op = &o.x;
#pragma unroll
            for (int nn = 0; nn < 4; ++nn) {
                float dd = f0v[nn] * ya + f1v[nn] * yb + f2v[nn] * yc;
                op[nn] = acc[mm][nn] * dd;
            }
            *(float4*)&in0s[(size_t)e * 160 + 128 + c] = o;
        } else if (r < 288) {
            const int c = r - 160;
            const float4 xv = *(const float4*)&x0[j * 128 + c];
            float4 o;
            o.x = acc[mm][0] * xv.x; o.y = acc[mm][1] * xv.y;
            o.z = acc[mm][2] * xv.z; o.w = acc[mm][3] * xv.w;
            *(float4*)&inUs[(size_t)e * 128 + c] = o;
        } else {
            const int c = (r < 320) ? (r - 288) : (r < 352) ? (r - 320) : (r - 352);
            float4 p0 = *(const float4*)&x1p[0 * PL + j * 32 + c];
            float4 p1 = *(const float4*)&x1p[1 * PL + j * 32 + c];
            float4 p2 = *(const float4*)&x1p[2 * PL + j * 32 + c];
            const float* f0v = &p0.x; const float* f1v = &p1.x; const float* f2v = &p2.x;
            float w0[4], w1[4], w2[4];
            int off;
            if (r < 320) {
                off = 0;
#pragma unroll
                for (int nn = 0; nn < 4; ++nn) {
                    w0[nn] = acc[mm][nn] * f0v[nn];
                    w1[nn] = acc[mm][nn] * f1v[nn];
                    w2[nn] = acc[mm][nn] * f2v[nn];
                }
            } else if (r < 352) {
                off = 32;
#pragma unroll
                for (int nn = 0; nn < 4; ++nn) {
                    float fx = f0v[nn], fy = f1v[nn], fz = f2v[nn];
                    w0[nn] = acc[mm][nn] * (fy * yc - fz * yb);
                    w1[nn] = acc[mm][nn] * (fz * ya - fx * yc);
                    w2[nn] = acc[mm][nn] * (fx * yb - fy * ya);
                }
            } else {
                off = 64;
#pragma unroll
                for (int nn = 0; nn < 4; ++nn) {
                    float fx = f0v[nn], fy = f1v[nn], fz = f2v[nn];
                    float dd = fx * ya + fy * yb + fz * yc;
                    w0[nn] = acc[mm][nn] * (ya * dd - fx * (1.0f / 3.0f));
                    w1[nn] = acc[mm][nn] * (yb * dd - fy * (1.0f / 3.0f));
                    w2[nn] = acc[mm][nn] * (yc * dd - fz * (1.0f / 3.0f));
                }
            }
            *(float4*)&inWs[((size_t)0 * ENUM + e) * 96 + off + c] = make_float4(w0[0], w0[1], w0[2], w0[3]);
            *(float4*)&inWs[((size_t)1 * ENUM + e) * 96 + off + c] = make_float4(w1[0], w1[1], w1[2], w1[3]);
            *(float4*)&inWs[((size_t)2 * ENUM + e) * 96 + off + c] = make_float4(w2[0], w2[1], w2[2], w2[3]);
        }
    }
}

// =====================================================================
//  Multi-job tiled f32 GEMM: C = A[M,K] @ B[N,K]^T, row-major, BM=128.
//  epi: 0 store, 1 rank1-add (k1: +U[e][n]*y1[e][m]), 2 gelu-store,
//       3 residual (C += al[0]*acc).  am>=0: A-load applies h1 phase-norm
//  over 3 planes (stride HPL), using plane am.
// =====================================================================
struct GJob {
    const float* A; const float* B; float* C; const float* U; const float* al;
    int ntiles, mtiles, N, K, lda, ldb, ldc, epi, am;
};
struct GJobs { GJob j[8]; int n; };

template <int BN, int TN>
__global__ __launch_bounds__(256) void gemm_multi(GJobs js, const float* __restrict__ y1) {
    constexpr int BM = 128, BK = 32, TM = 8;
    __shared__ float As[BK][BM + 8];
    __shared__ float Bs[BK][BN + 8];
    const int t = threadIdx.x;
    const int bid = blockIdx.x;
    GJob jb; int rel = 0;
    {
        int base = 0;
#pragma unroll 1
        for (int i = 0; i < js.n; ++i) {
            int nt = js.j[i].ntiles;
            if (bid >= base && bid < base + nt) { jb = js.j[i]; rel = bid - base; }
            base += nt;
        }
    }
    const int mt = rel % jb.mtiles, ntc = rel / jb.mtiles;
    const int m0 = mt * BM, n0 = ntc * BN;
    const int tm = (t / (BN / TN)) * TM;
    const int tn = (t % (BN / TN)) * TN;
    float acc[TM][TN] = {};
    for (int kc = 0; kc < jb.K; kc += BK) {
#pragma unroll
        for (int i = 0; i < 4; ++i) {
            int f = t + 256 * i;
            int m = f >> 3, k4 = (f & 7) * 4;
            float4 a;
            if (jb.am < 0) {
                a = *(const float4*)&jb.A[(size_t)(m0 + m) * jb.lda + kc + k4];
            } else {
                size_t i0 = (size_t)(m0 + m) * jb.lda + kc + k4;
                float4 v0 = *(const float4*)&jb.A[i0];
                float4 v1 = *(const float4*)&jb.A[i0 + HPL];
                float4 v2 = *(const float4*)&jb.A[i0 + 2 * HPL];
                float4 vm = (jb.am == 0) ? v0 : (jb.am == 1) ? v1 : v2;
                const float* q0 = &v0.x; const float* q1 = &v1.x; const float* q2 = &v2.x;
                const float* qm = &vm.x; float* pa = &a.x;
#pragma unroll
                for (int q = 0; q < 4; ++q) {
                    float nh = sqrtf(q0[q] * q0[q] + q1[q] * q1[q] + q2[q] * q2[q]);
                    pa[q] = qm[q] * (gelu_f(nh) / (nh + 1e-6f));
                }
            }
            As[k4 + 0][m] = a.x; As[k4 + 1][m] = a.y; As[k4 + 2][m] = a.z; As[k4 + 3][m] = a.w;
        }
#pragma unroll
        for (int i = 0; i < (BN * BK) / 1024; ++i) {
            int f = t + 256 * i;
            int n = f >> 3, k4 = (f & 7) * 4;
            float4 b = make_float4(0.f, 0.f, 0.f, 0.f);
            if (n0 + n < jb.N) b = *(const float4*)&jb.B[(size_t)(n0 + n) * jb.ldb + kc + k4];
            Bs[k4 + 0][n] = b.x; Bs[k4 + 1][n] = b.y; Bs[k4 + 2][n] = b.z; Bs[k4 + 3][n] = b.w;
        }
        __syncthreads();
#pragma unroll
        for (int k = 0; k < BK; ++k) {
            float a[TM], b[TN];
            *(float4*)&a[0] = *(const float4*)&As[k][tm];
            *(float4*)&a[4] = *(const float4*)&As[k][tm + 4];
            if (TN == 4) *(float4*)&b[0] = *(const float4*)&Bs[k][tn];
            else         *(float2*)&b[0] = *(const float2*)&Bs[k][tn];
#pragma unroll
            for (int mm = 0; mm < TM; ++mm)
#pragma unroll
                for (int nn = 0; nn < TN; ++nn) acc[mm][nn] += a[mm] * b[nn];
        }
        __syncthreads();
    }
    const int cn = n0 + tn;
    if (cn >= jb.N) return;
    float al = (jb.epi == 3) ? jb.al[0] : 0.f;
#pragma unroll
    for (int mm = 0; mm < TM; ++mm) {
        const int row = m0 + tm + mm;
        float o[TN];
        if (jb.epi == 1) {
            int m = row >> 14, e = row & 16383;
            float yv = y1[e * 3 + m];
#pragma unroll
            for (int nn = 0; nn < TN; ++nn) o[nn] = acc[mm][nn] + jb.U[e * 32 + cn + nn] * yv;
        } else if (jb.epi == 2) {
#pragma unroll
            for (int nn = 0; nn < TN; ++nn) o[nn] = gelu_f(acc[mm][nn]);
        } else if (jb.epi == 3) {
            if (TN == 4) {
                float4 old = *(const float4*)&jb.C[(size_t)row * jb.ldc + cn];
                o[0] = old.x + al * acc[mm][0]; o[1] = old.y + al * acc[mm][1];
                o[2] = old.z + al * acc[mm][2]; o[3] = old.w + al * acc[mm][3];
            } else {
                float2 old = *(const float2*)&jb.C[(size_t)row * jb.ldc + cn];
                o[0] = old.x + al * acc[mm][0]; o[1] = old.y + al * acc[mm][1];
            }
        } else {
#pragma unroll
            for (int nn = 0; nn < TN; ++nn) o[nn] = acc[mm][nn];
        }
        if (TN == 4) *(float4*)&jb.C[(size_t)row * jb.ldc + cn] = make_float4(o[0], o[1], o[2], o[3]);
        else         *(float2*)&jb.C[(size_t)row * jb.ldc + cn] = make_float2(o[0], o[1]);
    }
}

// ---------------- attention core (logits+softmax+weighted sum) ----------------
__global__ __launch_bounds__(256) void attn_core(const float* __restrict__ q0,
                                                 const float* __restrict__ q1p,
                                                 const float* __restrict__ k0,
                                                 const float* __restrict__ k1,
                                                 const float* __restrict__ v0,
                                                 const float* __restrict__ v1,
                                                 const float* __restrict__ biasb,
                                                 const float* __restrict__ maskf,
                                                 float* __restrict__ o0,
                                                 float* __restrict__ o1p) {
    __shared__ float q0s[4][128];
    __shared__ float q1s[4][96];
    __shared__ float attns[4][64];
    const int wid = threadIdx.x >> 6, lane = threadIdx.x & 63;
    const int n = blockIdx.x * 4 + wid;
    q0s[wid][lane]      = q0[n * 128 + lane];
    q0s[wid][lane + 64] = q0[n * 128 + lane + 64];
    if (lane < 32) {
#pragma unroll
        for (int m = 0; m < 3; ++m) q1s[wid][m * 32 + lane] = q1p[m * PL + n * 32 + lane];
    }
    __syncthreads();
    const int h = lane >> 4, k = lane & 15;
    const int e = n * KK + k;
    float acc = 0.f;
    for (int c = 0; c < 32; ++c) acc += q0s[wid][h * 32 + c] * k0[e * 128 + h * 32 + c];
#pragma unroll
    for (int m = 0; m < 3; ++m)
        for (int c = 0; c < 8; ++c)
            acc += q1s[wid][m * 32 + h * 8 + c] * k1[((size_t)m * ENUM + e) * 32 + h * 8 + c];
    acc = acc * SCALE_ATTN + biasb[e * 4 + h];
    if (maskf[e] == 0.0f) acc = -1e9f;
    float mx = gmax16(acc);
    float ex = expf(acc - mx);
    float sm = gsum16(ex);
    attns[wid][lane] = ex / sm;
    __syncthreads();
#pragma unroll
    for (int t = 0; t < 2; ++t) {
        int oc = lane + 64 * t;
        int h2 = oc >> 5;
        float a = 0.f;
        for (int kk = 0; kk < KK; ++kk) a += attns[wid][h2 * 16 + kk] * v0[(n * KK + kk) * 128 + oc];
        o0[n * 128 + oc] = a;
    }
    for (int val = lane; val < 96; val += 64) {
        int cc = val & 31, m = val >> 5;
        int h2 = cc >> 3;
        float a = 0.f;
        for (int kk = 0; kk < KK; ++kk)
            a += attns[wid][h2 * 16 + kk] * v1[((size_t)m * ENUM + n * KK + kk) * 32 + cc];
        o1p[m * PL + n * 32 + cc] = a;
    }
}

// ---------------- coords output ----------------
__global__ __launch_bounds__(256) void out_c_kernel(const float* __restrict__ f1p,
                                                    const float* __restrict__ coords,
                                                    const float* __restrict__ Wp1,
                                                    float* __restrict__ out) {
    int g = blockIdx.x * 256 + threadIdx.x;
    if (g >= NN * 9) return;
    int n = g / 9, r = g % 9, o = r / 3, m = r % 3;
    float a = coords[(n * 4 + 1) * 3 + m];
    for (int c = 0; c < 32; ++c) a += Wp1[o * 32 + c] * f1p[m * PL + n * 32 + c];
    out[NN * 128 + (n * 3 + o) * 3 + m] = a;
}

static inline GJob mk(const float* A, const float* B, float* C, int N, int K,
                      int lda, int ldb, int ldc, int mtiles, int ntiles, int epi,
                      const float* U = nullptr, const float* al = nullptr, int am = -1) {
    GJob j; j.A = A; j.B = B; j.C = C; j.U = U; j.al = al;
    j.ntiles = ntiles; j.mtiles = mtiles; j.N = N; j.K = K;
    j.lda = lda; j.ldb = ldb; j.ldc = ldc; j.epi = epi; j.am = am;
    return j;
}

extern "C" void kernel_launch(void* const* d_in, const int* in_sizes, int n_in,
                              void* d_out, int out_size, void* d_ws, size_t ws_size,
                              hipStream_t stream) {
    (void)in_sizes; (void)n_in; (void)out_size; (void)ws_size;
    const float* node_feats = (const float*)d_in[0];
    const float* pair       = (const float*)d_in[1];
    const float* coords     = (const float*)d_in[2];
    const float* eln_g      = (const float*)d_in[3];
    const float* eln_b      = (const float*)d_in[4];
    const float* Wi0        = (const float*)d_in[5];
    const float* Wi1        = (const float*)d_in[6];
    const float* ln0_g      = (const float*)d_in[7];
    const float* ln0_b      = (const float*)d_in[8];
    const float* n1_g       = (const float*)d_in[9];
    const float* n1_b       = (const float*)d_in[10];
    const float* Wq0        = (const float*)d_in[11];
    const float* Wq1        = (const float*)d_in[12];
    const float* WrK        = (const float*)d_in[13];
    const float* WrV        = (const float*)d_in[14];
    const float* WkA        = (const float*)d_in[15];
    const float* WkB        = (const float*)d_in[16];
    const float* WvA        = (const float*)d_in[17];
    const float* WvB        = (const float*)d_in[18];
    const float* Wb         = (const float*)d_in[19];
    const float* Wo0        = (const float*)d_in[20];
    const float* Wo1        = (const float*)d_in[21];
    const float* alpha_attn = (const float*)d_in[22];
    const float* lnf0_g     = (const float*)d_in[23];
    const float* lnf0_b     = (const float*)d_in[24];
    const float* nf1_g      = (const float*)d_in[25];
    const float* nf1_b      = (const float*)d_in[26];
    const float* Wf0a       = (const float*)d_in[27];
    const float* Wf0b       = (const float*)d_in[28];
    const float* Wf1a       = (const float*)d_in[29];
    const float* Wf1b       = (const float*)d_in[30];
    const float* alpha_ff   = (const float*)d_in[31];
    const float* Wp0        = (const float*)d_in[32];
    const float* Wp1        = (const float*)d_in[33];
    float* out = (float*)d_out;

    float* ws = (float*)d_ws;
    size_t off = 0;
    int*   idx   = (int*)(ws + off); off += NN * KK;
    float* maskf = ws + off;         off += NN * KK;
    float* y1    = ws + off;         off += NN * KK * 3;
    float* edges = ws + off;         off += (size_t)ENUM * EDc;
    float* f0    = ws + off;         off += NN * C0c;
    float* f1p   = ws + off;         off += 3 * PL;
    float* x0    = ws + off;         off += NN * C0c;
    float* x1p   = ws + off;         off += 3 * PL;
    float* q0    = ws + off;         off += NN * C0c;
    float* q1p   = ws + off;         off += 3 * PL;
    float* k0    = ws + off;         off += (size_t)ENUM * C0c;
    float* k1    = ws + off;         off += (size_t)ENUM * C1c * 3;
    float* v0    = ws + off;         off += (size_t)ENUM * C0c;
    float* v1    = ws + off;         off += (size_t)ENUM * C1c * 3;
    float* in0   = ws + off;         off += (size_t)2 * ENUM * 160;
    float* inU   = ws + off;         off += (size_t)2 * ENUM * 128;
    float* inW   = ws + off;         off += (size_t)2 * 3 * ENUM * 96;
    float* u     = ws + off;         off += (size_t)2 * ENUM * 32;
    float* biasb = ws + off;         off += (size_t)ENUM * 4;
    float* o0    = ws + off;         off += NN * C0c;
    float* o1p   = ws + off;         off += 3 * PL;
    float* h0    = ws + off;         off += (size_t)NN * 512;
    float* h1t   = ws + off;         off += (size_t)3 * HPL;

    knn_kernel2<<<NN / 4, 256, 0, stream>>>(coords, idx, maskf, y1);
    f1init_kernel<<<(NN * 32 + 255) / 256, 256, 0, stream>>>(coords, Wi1, f1p);
    edge_ln_kernel<<<ENUM / 4, 256, 0, stream>>>(pair, idx, eln_g, eln_b, edges);
    {   // f0 = node_feats @ Wi0^T
        GJobs js; js.n = 1;
        js.j[0] = mk(node_feats, Wi0, f0, 128, 128, 128, 128, 128, 8, 16, 0);
        gemm_multi<64, 4><<<16, 256, 0, stream>>>(js, y1);
    }

    for (int l = 0; l < Lc; ++l) {
        const float* Wq0l = Wq0 + (size_t)l * 128 * 128;
        const float* Wq1l = Wq1 + (size_t)l * 32 * 32;
        const float* WrKl = WrK + (size_t)l * 384 * 64;
        const float* WrVl = WrV + (size_t)l * 384 * 64;
        const float* WkAl = WkA + (size_t)l * 128 * 160;
        const float* WvAl = WvA + (size_t)l * 128 * 160;
        const float* WkBl = WkB + (size_t)l * 32 * 224;
        const float* WvBl = WvB + (size_t)l * 32 * 224;
        const float* Wbl  = Wb  + (size_t)l * 4 * 64;
        const float* Wo0l = Wo0 + (size_t)l * 128 * 128;
        const float* Wo1l = Wo1 + (size_t)l * 32 * 32;
        const float* Wf0al = Wf0a + (size_t)l * 512 * 128;
        const float* Wf0bl = Wf0b + (size_t)l * 128 * 512;
        const float* Wf1al = Wf1a + (size_t)l * 128 * 32;
        const float* Wf1bl = Wf1b + (size_t)l * 32 * 128;

        fnorm_kernel<<<NN / 4, 256, 0, stream>>>(f0, f1p,
            ln0_g + l * 128, ln0_b + l * 128, n1_g + l * 32, n1_b + l * 32, x0, x1p);

        radial_kv<<<dim3(ENUM / 128, 6, 2), 256, 0, stream>>>(
            edges, WrKl, WrVl, x0, x1p, idx, y1, in0, inU, inW);

        {   // gemmA: k0(K,V), u(K,V), q0, q1 planes
            GJobs js; js.n = 8;
            js.j[0] = mk(in0,                  WkAl, k0, 128, 160, 160, 160, 128, 128, 256, 0);
            js.j[1] = mk(in0 + (size_t)ENUM * 160, WvAl, v0, 128, 160, 160, 160, 128, 128, 256, 0);
            js.j[2] = mk(inU,                  WkBl, u,            32, 128, 128, 224, 32, 128, 128, 0);
            js.j[3] = mk(inU + (size_t)ENUM * 128, WvBl, u + ENUM * 32, 32, 128, 128, 224, 32, 128, 128, 0);
            js.j[4] = mk(x0, Wq0l, q0, 128, 128, 128, 128, 128, 8, 16, 0);
            js.j[5] = mk(x1p + 0 * PL, Wq1l, q1p + 0 * PL, 32, 32, 32, 32, 32, 8, 8, 0);
            js.j[6] = mk(x1p + 1 * PL, Wq1l, q1p + 1 * PL, 32, 32, 32, 32, 32, 8, 8, 0);
            js.j[7] = mk(x1p + 2 * PL, Wq1l, q1p + 2 * PL, 32, 32, 32, 32, 32, 8, 8, 0);
            gemm_multi<64, 4><<<808, 256, 0, stream>>>(js, y1);
        }
        {   // gemmC: k1(K,V) with rank-1 epilogue, attn bias
            GJobs js; js.n = 3;
            js.j[0] = mk(inW,                       WkBl + 128, k1, 32, 96, 96, 224, 32, 384, 384, 1, u);
            js.j[1] = mk(inW + (size_t)3 * ENUM * 96, WvBl + 128, v1, 32, 96, 96, 224, 32, 384, 384, 1, u + ENUM * 32);
            js.j[2] = mk(edges, Wbl, biasb, 4, 64, 64, 64, 4, 128, 128, 0);
            gemm_multi<32, 2><<<896, 256, 0, stream>>>(js, y1);
        }
        attn_core<<<NN / 4, 256, 0, stream>>>(q0, q1p, k0, k1, v0, v1, biasb, maskf, o0, o1p);
        {   // output projections + rezero residual
            GJobs js; js.n = 4;
            js.j[0] = mk(o0, Wo0l, f0, 128, 128, 128, 128, 128, 8, 16, 3, nullptr, alpha_attn + l);
            js.j[1] = mk(o1p + 0 * PL, Wo1l, f1p + 0 * PL, 32, 32, 32, 32, 32, 8, 8, 3, nullptr, alpha_attn + l);
            js.j[2] = mk(o1p + 1 * PL, Wo1l, f1p + 1 * PL, 32, 32, 32, 32, 32, 8, 8, 3, nullptr, alpha_attn + l);
            js.j[3] = mk(o1p + 2 * PL, Wo1l, f1p + 2 * PL, 32, 32, 32, 32, 32, 8, 8, 3, nullptr, alpha_attn + l);
            gemm_multi<64, 4><<<40, 256, 0, stream>>>(js, y1);
        }
        fnorm_kernel<<<NN / 4, 256, 0, stream>>>(f0, f1p,
            lnf0_g + l * 128, lnf0_b + l * 128, nf1_g + l * 32, nf1_b + l * 32, x0, x1p);
        {   // ff gemm1: h0 = gelu(x0@Wf0a^T), h1t[m] = x1p[m]@Wf1a^T
            GJobs js; js.n = 4;
            js.j[0] = mk(x0, Wf0al, h0, 512, 128, 128, 128, 512, 8, 64, 2);
            js.j[1] = mk(x1p + 0 * PL, Wf1al, h1t + 0 * HPL, 128, 32, 32, 32, 128, 8, 16, 0);
            js.j[2] = mk(x1p + 1 * PL, Wf1al, h1t + 1 * HPL, 128, 32, 32, 32, 128, 8, 16, 0);
            js.j[3] = mk(x1p + 2 * PL, Wf1al, h1t + 2 * HPL, 128, 32, 32, 32, 128, 8, 16, 0);
            gemm_multi<64, 4><<<112, 256, 0, stream>>>(js, y1);
        }
        {   // ff gemm2: f0 += a*h0@Wf0b^T, f1p[m] += a*(phase-normed h1t)@Wf1b^T
            GJobs js; js.n = 4;
            js.j[0] = mk(h0, Wf0bl, f0, 128, 512, 512, 512, 128, 8, 16, 3, nullptr, alpha_ff + l);
            js.j[1] = mk(h1t, Wf1bl, f1p + 0 * PL, 32, 128, 128, 128, 32, 8, 8, 3, nullptr, alpha_ff + l, 0);
            js.j[2] = mk(h1t, Wf1bl, f1p + 1 * PL, 32, 128, 128, 128, 32, 8, 8, 3, nullptr, alpha_ff + l, 1);
            js.j[3] = mk(h1t, Wf1bl, f1p + 2 * PL, 32, 128, 128, 128, 32, 8, 8, 3, nullptr, alpha_ff + l, 2);
            gemm_multi<64, 4><<<40, 256, 0, stream>>>(js, y1);
        }
    }

    {   // node_out = f0 @ Wp0^T
        GJobs js; js.n = 1;
        js.j[0] = mk(f0, Wp0, out, 128, 128, 128, 128, 128, 8, 16, 0);
        gemm_multi<64, 4><<<16, 256, 0, stream>>>(js, y1);
    }
    out_c_kernel<<<(NN * 9 + 255) / 256, 256, 0, stream>>>(f1p, coords, Wp1, out);
}

// Round 4
// 426.862 us; speedup vs baseline: 5.0054x; 1.1881x over previous
//
#include <hip/hip_runtime.h>
#include <hip/hip_bf16.h>
#include <math.h>

// ---- problem constants ----
static constexpr int NN  = 1024;
static constexpr int KK  = 16;
static constexpr int C0c = 128;
static constexpr int C1c = 32;
static constexpr int EDc = 64;
static constexpr int Lc  = 2;
static constexpr int ENUM = NN * KK;        // 16384 edges
static constexpr int PL   = NN * C1c;       // 32768: m-plane stride (f32 node tensors)
static constexpr int HPL  = NN * 128;       // m-plane stride for h1t
static constexpr int X1HS = NN * 32;        // bf16 x1 plane stride
#define SCALE_ATTN 0.13363062095621219f     /* 1/sqrt(32+3*8) */

typedef __attribute__((ext_vector_type(8))) short s8v;   // 8 bf16 (4 VGPRs)
typedef __attribute__((ext_vector_type(4))) float f4v;   // MFMA acc

__device__ __forceinline__ float wsum64(float v) {
    for (int o = 32; o > 0; o >>= 1) v += __shfl_xor(v, o);
    return v;
}
__device__ __forceinline__ float gsum16(float v) {
    for (int o = 8; o > 0; o >>= 1) v += __shfl_xor(v, o, 16);
    return v;
}
__device__ __forceinline__ float gmax16(float v) {
    for (int o = 8; o > 0; o >>= 1) v = fmaxf(v, __shfl_xor(v, o, 16));
    return v;
}
__device__ __forceinline__ float gelu_f(float x) {
    float x3 = x * x * x;
    return 0.5f * x * (1.0f + tanhf(0.7978845608028654f * (x + 0.044715f * x3)));
}
__device__ __forceinline__ unsigned short f2bf(float x) {
    union { float f; unsigned int u; } v; v.f = x;
    unsigned int r = v.u + 0x7fffu + ((v.u >> 16) & 1u);
    return (unsigned short)(r >> 16);
}
__device__ __forceinline__ s8v ld8(const unsigned short* p) {
    return *(const s8v*)p;
}
__device__ __forceinline__ f4v mfma16(s8v a, s8v b, f4v c) {
    return __builtin_amdgcn_mfma_f32_16x16x32_bf16(a, b, c, 0, 0, 0);
}

// ---------------- weight f32->bf16 conversion ----------------
struct CvJob { const float* s; unsigned short* d; int n; };
struct CvJobs { CvJob j[8]; int n; int total; };
__global__ __launch_bounds__(256) void cvt_kernel(CvJobs js) {
    int g = blockIdx.x * 256 + threadIdx.x;
    if (g >= js.total) return;
    for (int i = 0; i < js.n; ++i) {
        int n = js.j[i].n;
        if (g < n) { js.j[i].d[g] = f2bf(js.j[i].s[g]); return; }
        g -= n;
    }
}

// ---------------- kNN: wave per node, register distances ----------------
__global__ __launch_bounds__(256) void knn_kernel2(const float* __restrict__ coords,
                                                   int* __restrict__ idx,
                                                   float* __restrict__ maskf,
                                                   float* __restrict__ y1) {
    __shared__ float ca[NN * 3];
    const int tid = threadIdx.x;
    for (int f = tid; f < NN * 3; f += 256) {
        int i = f / 3, m = f % 3;
        ca[f] = coords[(i * 4 + 1) * 3 + m];
    }
    __syncthreads();
    const int wid = tid >> 6, lane = tid & 63;
    const int n = blockIdx.x * 4 + wid;
    const float cx = ca[n * 3 + 0], cy = ca[n * 3 + 1], cz = ca[n * 3 + 2];
    float d[16];
#pragma unroll
    for (int s = 0; s < 16; ++s) {
        int i = s * 64 + lane;
        float dx = cx - ca[i * 3 + 0], dy = cy - ca[i * 3 + 1], dz = cz - ca[i * 3 + 2];
        float d2 = dx * dx + dy * dy + dz * dz;
        d[s] = (i == n) ? 1e9f : d2;
    }
    for (int t = 0; t < KK; ++t) {
        float best = 1e30f; int bi = 0;
#pragma unroll
        for (int s = 0; s < 16; ++s) {
            int i = s * 64 + lane;
            float v = d[s];
            if (v < best || (v == best && i < bi)) { best = v; bi = i; }
        }
#pragma unroll
        for (int o = 32; o > 0; o >>= 1) {
            float ov = __shfl_xor(best, o);
            int   oi = __shfl_xor(bi, o);
            if (ov < best || (ov == best && oi < bi)) { best = ov; bi = oi; }
        }
        const int j = bi;
        if (lane == 0) {
            idx[n * KK + t] = j;
            float dist = sqrtf(best);
            maskf[n * KK + t] = (dist <= 16.0f) ? 1.0f : 0.0f;
            float rx = ca[j * 3 + 0] - cx, ry = ca[j * 3 + 1] - cy, rz = ca[j * 3 + 2] - cz;
            float nrm = sqrtf(rx * rx + ry * ry + rz * rz) + 1e-6f;
            y1[(n * KK + t) * 3 + 0] = rx / nrm;
            y1[(n * KK + t) * 3 + 1] = ry / nrm;
            y1[(n * KK + t) * 3 + 2] = rz / nrm;
        }
        const int js = j >> 6, jl = j & 63;
#pragma unroll
        for (int s = 0; s < 16; ++s)
            if (s == js && jl == lane) d[s] = 2e30f;
    }
}

// ---------------- edge gather + LN (bf16 out) + attn-bias for both layers ----------------
__global__ __launch_bounds__(256) void edge_ln_kernel(const float* __restrict__ pair,
                                                      const int* __restrict__ idx,
                                                      const float* __restrict__ g,
                                                      const float* __restrict__ b,
                                                      const float* __restrict__ Wb,
                                                      unsigned short* __restrict__ edges_h,
                                                      float* __restrict__ biasb) {
    const int wid = threadIdx.x >> 6, lane = threadIdx.x & 63;
    const int e = blockIdx.x * 4 + wid;
    const int n = e >> 4;
    const int j = idx[e];
    float v = pair[((size_t)n * NN + j) * EDc + lane];
    float m = wsum64(v) * (1.0f / 64.0f);
    float d = v - m;
    float var = wsum64(d * d) * (1.0f / 64.0f);
    float nv = d * rsqrtf(var + 1e-5f) * g[lane] + b[lane];
    edges_h[e * EDc + lane] = f2bf(nv);
#pragma unroll
    for (int l = 0; l < 2; ++l)
#pragma unroll
        for (int h = 0; h < 4; ++h) {
            float t = wsum64(nv * Wb[(l * 4 + h) * 64 + lane]);
            if (lane == 0) biasb[(size_t)l * ENUM * 4 + e * 4 + h] = t;
        }
}

// ---------------- f1 input projection (planes) ----------------
__global__ __launch_bounds__(256) void f1init_kernel(const float* __restrict__ coords,
                                                     const float* __restrict__ Wi1,
                                                     float* __restrict__ f1p) {
    int g = blockIdx.x * 256 + threadIdx.x;
    if (g >= NN * 32) return;
    int n = g >> 5, c = g & 31;
    float w0 = Wi1[c * 3 + 0], w1 = Wi1[c * 3 + 1], w2 = Wi1[c * 3 + 2];
#pragma unroll
    for (int m = 0; m < 3; ++m) {
        float cav = coords[(n * 4 + 1) * 3 + m];
        float a0 = coords[(n * 4 + 0) * 3 + m] - cav;
        float a1 = coords[(n * 4 + 2) * 3 + m] - cav;
        float a2 = coords[(n * 4 + 3) * 3 + m] - cav;
        f1p[m * PL + n * 32 + c] = w0 * a0 + w1 * a1 + w2 * a2;
    }
}

// ---------------- fiber norm (f32 + bf16 outputs) ----------------
__global__ __launch_bounds__(256) void fnorm_kernel(const float* __restrict__ f0,
                                                    const float* __restrict__ f1p,
                                                    const float* __restrict__ g0,
                                                    const float* __restrict__ b0,
                                                    const float* __restrict__ g1,
                                                    const float* __restrict__ b1,
                                                    float* __restrict__ x0,
                                                    float* __restrict__ x1p,
                                                    unsigned short* __restrict__ x0h,
                                                    unsigned short* __restrict__ x1h) {
    const int wid = threadIdx.x >> 6, lane = threadIdx.x & 63;
    const int n = blockIdx.x * 4 + wid;
    float va = f0[n * 128 + lane], vb = f0[n * 128 + lane + 64];
    float m = wsum64(va + vb) * (1.0f / 128.0f);
    float da = va - m, db = vb - m;
    float var = wsum64(da * da + db * db) * (1.0f / 128.0f);
    float rs = rsqrtf(var + 1e-5f);
    float xa = gelu_f(da * rs * g0[lane] + b0[lane]);
    float xb = gelu_f(db * rs * g0[lane + 64] + b0[lane + 64]);
    x0[n * 128 + lane]      = xa;
    x0[n * 128 + lane + 64] = xb;
    if (x0h) { x0h[n * 128 + lane] = f2bf(xa); x0h[n * 128 + lane + 64] = f2bf(xb); }
    int c = lane & 31;
    float h0 = f1p[0 * PL + n * 32 + c];
    float h1 = f1p[1 * PL + n * 32 + c];
    float h2 = f1p[2 * PL + n * 32 + c];
    float n1 = sqrtf(h0 * h0 + h1 * h1 + h2 * h2);
    float ms = wsum64(n1) * (1.0f / 64.0f);
    float dd = n1 - ms;
    float vv = wsum64(dd * dd) * (1.0f / 64.0f);
    float sc = gelu_f(dd * rsqrtf(vv + 1e-5f) * g1[c] + b1[c]) / (n1 + 1e-6f);
    if (lane < 32) {
        float o0v = h0 * sc, o1v = h1 * sc, o2v = h2 * sc;
        x1p[0 * PL + n * 32 + c] = o0v;
        x1p[1 * PL + n * 32 + c] = o1v;
        x1p[2 * PL + n * 32 + c] = o2v;
        if (x1h) {
            x1h[0 * X1HS + n * 32 + c] = f2bf(o0v);
            x1h[1 * X1HS + n * 32 + c] = f2bf(o1v);
            x1h[2 * X1HS + n * 32 + c] = f2bf(o2v);
        }
    }
}

// =====================================================================
//  Radial MFMA GEMM (K&V on blockIdx.z) with TFN pointwise epilogue.
//  R[e][r] = edges[e][:64] . Wr[r][:64]; branch on r-tile (blockIdx.y).
// =====================================================================
__global__ __launch_bounds__(256) void radial_mfma(const unsigned short* __restrict__ edges_h,
                                                   const unsigned short* __restrict__ WrK_h,
                                                   const unsigned short* __restrict__ WrV_h,
                                                   const float* __restrict__ x0,
                                                   const float* __restrict__ x1p,
                                                   const int* __restrict__ idx,
                                                   const float* __restrict__ y1,
                                                   unsigned short* __restrict__ in0,
                                                   unsigned short* __restrict__ inU,
                                                   unsigned short* __restrict__ inW) {
    const int t = threadIdx.x, w = t >> 6, l = t & 63;
    const int s = blockIdx.z;
    const unsigned short* Wr = s ? WrV_h : WrK_h;
    unsigned short* in0s = in0 + (size_t)s * ENUM * 160;
    unsigned short* inUs = inU + (size_t)s * ENUM * 128;
    unsigned short* inWs = inW + (size_t)s * 3 * ENUM * 96;
    const int e0w = blockIdx.x * 128 + w * 32;
    const int r0 = blockIdx.y * 32;
    const int c16 = l & 15, g8 = (l >> 4) * 8, g4 = (l >> 4) * 4;
    f4v acc[2][2];
#pragma unroll
    for (int a = 0; a < 2; ++a)
#pragma unroll
        for (int bq = 0; bq < 2; ++bq) acc[a][bq] = f4v{0.f, 0.f, 0.f, 0.f};
#pragma unroll
    for (int kc = 0; kc < 64; kc += 32) {
        s8v a0 = ld8(edges_h + (size_t)(e0w + c16) * 64 + kc + g8);
        s8v a1 = ld8(edges_h + (size_t)(e0w + 16 + c16) * 64 + kc + g8);
        s8v b0 = ld8(Wr + (size_t)(r0 + c16) * 64 + kc + g8);
        s8v b1 = ld8(Wr + (size_t)(r0 + 16 + c16) * 64 + kc + g8);
        acc[0][0] = mfma16(a0, b0, acc[0][0]);
        acc[0][1] = mfma16(a0, b1, acc[0][1]);
        acc[1][0] = mfma16(a1, b0, acc[1][0]);
        acc[1][1] = mfma16(a1, b1, acc[1][1]);
    }
#pragma unroll
    for (int fm = 0; fm < 2; ++fm)
#pragma unroll
        for (int r = 0; r < 4; ++r) {
            const int e = e0w + fm * 16 + g4 + r;
            const int j = idx[e];
            float ya = y1[e * 3 + 0], yb = y1[e * 3 + 1], yc = y1[e * 3 + 2];
#pragma unroll
            for (int fn = 0; fn < 2; ++fn) {
                const float av = acc[fm][fn][r];
                const int col = r0 + fn * 16 + c16;
                if (r0 < 128) {
                    in0s[(size_t)e * 160 + col] = f2bf(av * x0[j * 128 + col]);
                } else if (r0 < 160) {
                    int c = col - 128;
                    float d1 = x1p[0 * PL + j * 32 + c] * ya
                             + x1p[1 * PL + j * 32 + c] * yb
                             + x1p[2 * PL + j * 32 + c] * yc;
                    in0s[(size_t)e * 160 + col] = f2bf(av * d1);
                } else if (r0 < 288) {
                    int c = col - 160;
                    inUs[(size_t)e * 128 + c] = f2bf(av * x0[j * 128 + c]);
                } else if (r0 < 320) {
                    int c = col - 288;
                    float fx = x1p[0 * PL + j * 32 + c];
                    float fy = x1p[1 * PL + j * 32 + c];
                    float fz = x1p[2 * PL + j * 32 + c];
                    inWs[((size_t)0 * ENUM + e) * 96 + 0 + c] = f2bf(av * fx);
                    inWs[((size_t)1 * ENUM + e) * 96 + 0 + c] = f2bf(av * fy);
                    inWs[((size_t)2 * ENUM + e) * 96 + 0 + c] = f2bf(av * fz);
                } else if (r0 < 352) {
                    int c = col - 320;
                    float fx = x1p[0 * PL + j * 32 + c];
                    float fy = x1p[1 * PL + j * 32 + c];
                    float fz = x1p[2 * PL + j * 32 + c];
                    inWs[((size_t)0 * ENUM + e) * 96 + 32 + c] = f2bf(av * (fy * yc - fz * yb));
                    inWs[((size_t)1 * ENUM + e) * 96 + 32 + c] = f2bf(av * (fz * ya - fx * yc));
                    inWs[((size_t)2 * ENUM + e) * 96 + 32 + c] = f2bf(av * (fx * yb - fy * ya));
                } else {
                    int c = col - 352;
                    float fx = x1p[0 * PL + j * 32 + c];
                    float fy = x1p[1 * PL + j * 32 + c];
                    float fz = x1p[2 * PL + j * 32 + c];
                    float d1 = fx * ya + fy * yb + fz * yc;
                    inWs[((size_t)0 * ENUM + e) * 96 + 64 + c] = f2bf(av * (ya * d1 - fx * (1.0f / 3.0f)));
                    inWs[((size_t)1 * ENUM + e) * 96 + 64 + c] = f2bf(av * (yb * d1 - fy * (1.0f / 3.0f)));
                    inWs[((size_t)2 * ENUM + e) * 96 + 64 + c] = f2bf(av * (yc * d1 - fz * (1.0f / 3.0f)));
                }
            }
        }
}

// =====================================================================
//  Multi-job bf16 MFMA GEMM: C[M,N] f32 = A[M,K]bf16 @ B[N,K]^T bf16.
//  Block = 128 M-rows x 32 N-cols (4 waves stacked on M).
//  epi: 0 = store, 1 = rank1-add C = acc + U[e][n]*y1[e*3+plane].
// =====================================================================
struct HJob {
    const unsigned short* A; const unsigned short* B; float* C; const float* U;
    int ntiles, mtiles, K, lda, ldb, ldc, epi, pad;
};
struct HJobs { HJob j[8]; int n; };

__global__ __launch_bounds__(256) void hgemm_multi(HJobs js, const float* __restrict__ y1) {
    const int t = threadIdx.x, w = t >> 6, l = t & 63;
    const int bid = blockIdx.x;
    HJob jb; int rel = 0;
    {
        int base = 0;
#pragma unroll 1
        for (int i = 0; i < js.n; ++i) {
            int nt = js.j[i].ntiles;
            if (bid >= base && bid < base + nt) { jb = js.j[i]; rel = bid - base; }
            base += nt;
        }
    }
    const int mt = rel % jb.mtiles, ntc = rel / jb.mtiles;
    const int m0 = mt * 128 + w * 32;
    const int n0 = ntc * 32;
    const int c16 = l & 15, g8 = (l >> 4) * 8, g4 = (l >> 4) * 4;
    f4v acc[2][2];
#pragma unroll
    for (int a = 0; a < 2; ++a)
#pragma unroll
        for (int bq = 0; bq < 2; ++bq) acc[a][bq] = f4v{0.f, 0.f, 0.f, 0.f};
    const unsigned short* Ap = jb.A + (size_t)(m0 + c16) * jb.lda + g8;
    const unsigned short* Bp = jb.B + (size_t)(n0 + c16) * jb.ldb + g8;
    for (int kc = 0; kc < jb.K; kc += 32) {
        s8v a0 = ld8(Ap + kc);
        s8v a1 = ld8(Ap + 16 * jb.lda + kc);
        s8v b0 = ld8(Bp + kc);
        s8v b1 = ld8(Bp + 16 * jb.ldb + kc);
        acc[0][0] = mfma16(a0, b0, acc[0][0]);
        acc[0][1] = mfma16(a0, b1, acc[0][1]);
        acc[1][0] = mfma16(a1, b0, acc[1][0]);
        acc[1][1] = mfma16(a1, b1, acc[1][1]);
    }
#pragma unroll
    for (int fm = 0; fm < 2; ++fm)
#pragma unroll
        for (int r = 0; r < 4; ++r) {
            const int m = m0 + fm * 16 + g4 + r;
#pragma unroll
            for (int fn = 0; fn < 2; ++fn) {
                const int n = n0 + fn * 16 + c16;
                float v = acc[fm][fn][r];
                if (jb.epi == 1) {
                    int plane = m >> 14, e = m & 16383;
                    v += jb.U[e * 32 + n] * y1[e * 3 + plane];
                }
                jb.C[(size_t)m * jb.ldc + n] = v;
            }
        }
}

// =====================================================================
//  Multi-job tiled f32 GEMM (node-side ops).  epi: 0 store, 2 gelu,
//  3 residual (+al*acc).  am>=0: A-load applies h1 phase-norm (plane am).
// =====================================================================
struct GJob {
    const float* A; const float* B; float* C; const float* U; const float* al;
    int ntiles, mtiles, N, K, lda, ldb, ldc, epi, am;
};
struct GJobs { GJob j[8]; int n; };

template <int BN, int TN>
__global__ __launch_bounds__(256) void gemm_multi(GJobs js) {
    constexpr int BM = 128, BK = 32, TM = 8;
    __shared__ float As[BK][BM + 8];
    __shared__ float Bs[BK][BN + 8];
    const int t = threadIdx.x;
    const int bid = blockIdx.x;
    GJob jb; int rel = 0;
    {
        int base = 0;
#pragma unroll 1
        for (int i = 0; i < js.n; ++i) {
            int nt = js.j[i].ntiles;
            if (bid >= base && bid < base + nt) { jb = js.j[i]; rel = bid - base; }
            base += nt;
        }
    }
    const int mt = rel % jb.mtiles, ntc = rel / jb.mtiles;
    const int m0 = mt * BM, n0 = ntc * BN;
    const int tm = (t / (BN / TN)) * TM;
    const int tn = (t % (BN / TN)) * TN;
    float acc[TM][TN] = {};
    for (int kc = 0; kc < jb.K; kc += BK) {
#pragma unroll
        for (int i = 0; i < 4; ++i) {
            int f = t + 256 * i;
            int m = f >> 3, k4 = (f & 7) * 4;
            float4 a;
            if (jb.am < 0) {
                a = *(const float4*)&jb.A[(size_t)(m0 + m) * jb.lda + kc + k4];
            } else {
                size_t i0 = (size_t)(m0 + m) * jb.lda + kc + k4;
                float4 v0 = *(const float4*)&jb.A[i0];
                float4 v1 = *(const float4*)&jb.A[i0 + HPL];
                float4 v2 = *(const float4*)&jb.A[i0 + 2 * HPL];
                float4 vm = (jb.am == 0) ? v0 : (jb.am == 1) ? v1 : v2;
                const float* q0 = &v0.x; const float* q1 = &v1.x; const float* q2 = &v2.x;
                const float* qm = &vm.x; float* pa = &a.x;
#pragma unroll
                for (int q = 0; q < 4; ++q) {
                    float nh = sqrtf(q0[q] * q0[q] + q1[q] * q1[q] + q2[q] * q2[q]);
                    pa[q] = qm[q] * (gelu_f(nh) / (nh + 1e-6f));
                }
            }
            As[k4 + 0][m] = a.x; As[k4 + 1][m] = a.y; As[k4 + 2][m] = a.z; As[k4 + 3][m] = a.w;
        }
#pragma unroll
        for (int i = 0; i < (BN * BK) / 1024; ++i) {
            int f = t + 256 * i;
            int n = f >> 3, k4 = (f & 7) * 4;
            float4 b = make_float4(0.f, 0.f, 0.f, 0.f);
            if (n0 + n < jb.N) b = *(const float4*)&jb.B[(size_t)(n0 + n) * jb.ldb + kc + k4];
            Bs[k4 + 0][n] = b.x; Bs[k4 + 1][n] = b.y; Bs[k4 + 2][n] = b.z; Bs[k4 + 3][n] = b.w;
        }
        __syncthreads();
#pragma unroll
        for (int k = 0; k < BK; ++k) {
            float a[TM], b[TN];
            *(float4*)&a[0] = *(const float4*)&As[k][tm];
            *(float4*)&a[4] = *(const float4*)&As[k][tm + 4];
            if (TN == 4) *(float4*)&b[0] = *(const float4*)&Bs[k][tn];
            else         *(float2*)&b[0] = *(const float2*)&Bs[k][tn];
#pragma unroll
            for (int mm = 0; mm < TM; ++mm)
#pragma unroll
                for (int nn = 0; nn < TN; ++nn) acc[mm][nn] += a[mm] * b[nn];
        }
        __syncthreads();
    }
    const int cn = n0 + tn;
    if (cn >= jb.N) return;
    float al = (jb.epi == 3) ? jb.al[0] : 0.f;
#pragma unroll
    for (int mm = 0; mm < TM; ++mm) {
        const int row = m0 + tm + mm;
        float o[TN];
        if (jb.epi == 2) {
#pragma unroll
            for (int nn = 0; nn < TN; ++nn) o[nn] = gelu_f(acc[mm][nn]);
        } else if (jb.epi == 3) {
            if (TN == 4) {
                float4 old = *(const float4*)&jb.C[(size_t)row * jb.ldc + cn];
                o[0] = old.x + al * acc[mm][0]; o[1] = old.y + al * acc[mm][1];
                o[2] = old.z + al * acc[mm][2]; o[3] = old.w + al * acc[mm][3];
            } else {
                float2 old = *(const float2*)&jb.C[(size_t)row * jb.ldc + cn];
                o[0] = old.x + al * acc[mm][0]; o[1] = old.y + al * acc[mm][1];
            }
        } else {
#pragma unroll
            for (int nn = 0; nn < TN; ++nn) o[nn] = acc[mm][nn];
        }
        if (TN == 4) *(float4*)&jb.C[(size_t)row * jb.ldc + cn] = make_float4(o[0], o[1], o[2], o[3]);
        else         *(float2*)&jb.C[(size_t)row * jb.ldc + cn] = make_float2(o[0], o[1]);
    }
}

// ---------------- attention core ----------------
__global__ __launch_bounds__(256) void attn_core(const float* __restrict__ q0,
                                                 const float* __restrict__ q1p,
                                                 const float* __restrict__ k0,
                                                 const float* __restrict__ k1,
                                                 const float* __restrict__ v0,
                                                 const float* __restrict__ v1,
                                                 const float* __restrict__ biasb,
                                                 const float* __restrict__ maskf,
                                                 float* __restrict__ o0,
                                                 float* __restrict__ o1p) {
    __shared__ float q0s[4][128];
    __shared__ float q1s[4][96];
    __shared__ float attns[4][64];
    const int wid = threadIdx.x >> 6, lane = threadIdx.x & 63;
    const int n = blockIdx.x * 4 + wid;
    q0s[wid][lane]      = q0[n * 128 + lane];
    q0s[wid][lane + 64] = q0[n * 128 + lane + 64];
    if (lane < 32) {
#pragma unroll
        for (int m = 0; m < 3; ++m) q1s[wid][m * 32 + lane] = q1p[m * PL + n * 32 + lane];
    }
    __syncthreads();
    const int h = lane >> 4, k = lane & 15;
    const int e = n * KK + k;
    float acc = 0.f;
    for (int c = 0; c < 32; ++c) acc += q0s[wid][h * 32 + c] * k0[e * 128 + h * 32 + c];
#pragma unroll
    for (int m = 0; m < 3; ++m)
        for (int c = 0; c < 8; ++c)
            acc += q1s[wid][m * 32 + h * 8 + c] * k1[((size_t)m * ENUM + e) * 32 + h * 8 + c];
    acc = acc * SCALE_ATTN + biasb[e * 4 + h];
    if (maskf[e] == 0.0f) acc = -1e9f;
    float mx = gmax16(acc);
    float ex = expf(acc - mx);
    float sm = gsum16(ex);
    attns[wid][lane] = ex / sm;
    __syncthreads();
#pragma unroll
    for (int t = 0; t < 2; ++t) {
        int oc = lane + 64 * t;
        int h2 = oc >> 5;
        float a = 0.f;
        for (int kk = 0; kk < KK; ++kk) a += attns[wid][h2 * 16 + kk] * v0[(n * KK + kk) * 128 + oc];
        o0[n * 128 + oc] = a;
    }
    for (int val = lane; val < 96; val += 64) {
        int cc = val & 31, m = val >> 5;
        int h2 = cc >> 3;
        float a = 0.f;
        for (int kk = 0; kk < KK; ++kk)
            a += attns[wid][h2 * 16 + kk] * v1[((size_t)m * ENUM + n * KK + kk) * 32 + cc];
        o1p[m * PL + n * 32 + cc] = a;
    }
}

// ---------------- coords output ----------------
__global__ __launch_bounds__(256) void out_c_kernel(const float* __restrict__ f1p,
                                                    const float* __restrict__ coords,
                                                    const float* __restrict__ Wp1,
                                                    float* __restrict__ out) {
    int g = blockIdx.x * 256 + threadIdx.x;
    if (g >= NN * 9) return;
    int n = g / 9, r = g % 9, o = r / 3, m = r % 3;
    float a = coords[(n * 4 + 1) * 3 + m];
    for (int c = 0; c < 32; ++c) a += Wp1[o * 32 + c] * f1p[m * PL + n * 32 + c];
    out[NN * 128 + (n * 3 + o) * 3 + m] = a;
}

static inline GJob mkg(const float* A, const float* B, float* C, int N, int K,
                       int lda, int ldb, int ldc, int mtiles, int ntiles, int epi,
                       const float* al = nullptr, int am = -1) {
    GJob j; j.A = A; j.B = B; j.C = C; j.U = nullptr; j.al = al;
    j.ntiles = ntiles; j.mtiles = mtiles; j.N = N; j.K = K;
    j.lda = lda; j.ldb = ldb; j.ldc = ldc; j.epi = epi; j.am = am;
    return j;
}
static inline HJob mkh(const unsigned short* A, const unsigned short* B, float* C,
                       int mtiles, int ncols, int K, int lda, int ldb, int ldc,
                       int epi, const float* U = nullptr) {
    HJob j; j.A = A; j.B = B; j.C = C; j.U = U;
    j.mtiles = mtiles; j.ntiles = mtiles * (ncols / 32); j.K = K;
    j.lda = lda; j.ldb = ldb; j.ldc = ldc; j.epi = epi; j.pad = 0;
    return j;
}

extern "C" void kernel_launch(void* const* d_in, const int* in_sizes, int n_in,
                              void* d_out, int out_size, void* d_ws, size_t ws_size,
                              hipStream_t stream) {
    (void)in_sizes; (void)n_in; (void)out_size; (void)ws_size;
    const float* node_feats = (const float*)d_in[0];
    const float* pair       = (const float*)d_in[1];
    const float* coords     = (const float*)d_in[2];
    const float* eln_g      = (const float*)d_in[3];
    const float* eln_b      = (const float*)d_in[4];
    const float* Wi0        = (const float*)d_in[5];
    const float* Wi1        = (const float*)d_in[6];
    const float* ln0_g      = (const float*)d_in[7];
    const float* ln0_b      = (const float*)d_in[8];
    const float* n1_g       = (const float*)d_in[9];
    const float* n1_b       = (const float*)d_in[10];
    const float* Wq0        = (const float*)d_in[11];
    const float* Wq1        = (const float*)d_in[12];
    const float* WrK        = (const float*)d_in[13];
    const float* WrV        = (const float*)d_in[14];
    const float* WkA        = (const float*)d_in[15];
    const float* WkB        = (const float*)d_in[16];
    const float* WvA        = (const float*)d_in[17];
    const float* WvB        = (const float*)d_in[18];
    const float* Wb         = (const float*)d_in[19];
    const float* Wo0        = (const float*)d_in[20];
    const float* Wo1        = (const float*)d_in[21];
    const float* alpha_attn = (const float*)d_in[22];
    const float* lnf0_g     = (const float*)d_in[23];
    const float* lnf0_b     = (const float*)d_in[24];
    const float* nf1_g      = (const float*)d_in[25];
    const float* nf1_b      = (const float*)d_in[26];
    const float* Wf0a       = (const float*)d_in[27];
    const float* Wf0b       = (const float*)d_in[28];
    const float* Wf1a       = (const float*)d_in[29];
    const float* Wf1b       = (const float*)d_in[30];
    const float* alpha_ff   = (const float*)d_in[31];
    const float* Wp0        = (const float*)d_in[32];
    const float* Wp1        = (const float*)d_in[33];
    float* out = (float*)d_out;

    float* ws = (float*)d_ws;
    size_t off = 0;
    int*   idx   = (int*)(ws + off); off += NN * KK;
    float* maskf = ws + off;         off += NN * KK;
    float* y1    = ws + off;         off += NN * KK * 3;
    float* f0    = ws + off;         off += NN * C0c;
    float* f1p   = ws + off;         off += 3 * PL;
    float* x0    = ws + off;         off += NN * C0c;
    float* x1p   = ws + off;         off += 3 * PL;
    float* q0    = ws + off;         off += NN * C0c;
    float* q1p   = ws + off;         off += 3 * PL;
    float* k0    = ws + off;         off += (size_t)ENUM * C0c;
    float* k1    = ws + off;         off += (size_t)3 * ENUM * C1c;
    float* v0    = ws + off;         off += (size_t)ENUM * C0c;
    float* v1    = ws + off;         off += (size_t)3 * ENUM * C1c;
    float* u     = ws + off;         off += (size_t)2 * ENUM * 32;
    float* biasb = ws + off;         off += (size_t)2 * ENUM * 4;
    float* o0    = ws + off;         off += NN * C0c;
    float* o1p   = ws + off;         off += 3 * PL;
    float* h0    = ws + off;         off += (size_t)NN * 512;
    float* h1t   = ws + off;         off += (size_t)3 * HPL;
    off = (off + 3) & ~(size_t)3;                       // 16B align for bf16 pool
    unsigned short* up = (unsigned short*)(ws + off);
    size_t uo = 0;
    unsigned short* edges_h = up + uo; uo += (size_t)ENUM * 64;
    unsigned short* in0h    = up + uo; uo += (size_t)2 * ENUM * 160;
    unsigned short* inUh    = up + uo; uo += (size_t)2 * ENUM * 128;
    unsigned short* inWh    = up + uo; uo += (size_t)2 * 3 * ENUM * 96;
    unsigned short* x0h     = up + uo; uo += (size_t)NN * 128;
    unsigned short* x1h     = up + uo; uo += (size_t)3 * X1HS;
    unsigned short* WrK_h   = up + uo; uo += 2 * 24576;
    unsigned short* WrV_h   = up + uo; uo += 2 * 24576;
    unsigned short* WkA_h   = up + uo; uo += 2 * 20480;
    unsigned short* WvA_h   = up + uo; uo += 2 * 20480;
    unsigned short* WkB_h   = up + uo; uo += 2 * 7168;
    unsigned short* WvB_h   = up + uo; uo += 2 * 7168;
    unsigned short* Wq0_h   = up + uo; uo += 2 * 16384;
    unsigned short* Wq1_h   = up + uo; uo += 2 * 1024;

    {   // weight conversion
        CvJobs cj; cj.n = 8;
        cj.j[0] = {WrK, WrK_h, 2 * 24576};
        cj.j[1] = {WrV, WrV_h, 2 * 24576};
        cj.j[2] = {WkA, WkA_h, 2 * 20480};
        cj.j[3] = {WvA, WvA_h, 2 * 20480};
        cj.j[4] = {WkB, WkB_h, 2 * 7168};
        cj.j[5] = {WvB, WvB_h, 2 * 7168};
        cj.j[6] = {Wq0, Wq0_h, 2 * 16384};
        cj.j[7] = {Wq1, Wq1_h, 2 * 1024};
        cj.total = 2 * (24576 * 2 + 20480 * 2 + 7168 * 2 + 16384 + 1024);
        cvt_kernel<<<(cj.total + 255) / 256, 256, 0, stream>>>(cj);
    }
    knn_kernel2<<<NN / 4, 256, 0, stream>>>(coords, idx, maskf, y1);
    f1init_kernel<<<(NN * 32 + 255) / 256, 256, 0, stream>>>(coords, Wi1, f1p);
    edge_ln_kernel<<<ENUM / 4, 256, 0, stream>>>(pair, idx, eln_g, eln_b, Wb, edges_h, biasb);
    {   // f0 = node_feats @ Wi0^T
        GJobs js; js.n = 1;
        js.j[0] = mkg(node_feats, Wi0, f0, 128, 128, 128, 128, 128, 8, 16, 0);
        gemm_multi<64, 4><<<16, 256, 0, stream>>>(js);
    }

    for (int l = 0; l < Lc; ++l) {
        const unsigned short* WrKl = WrK_h + (size_t)l * 24576;
        const unsigned short* WrVl = WrV_h + (size_t)l * 24576;
        const unsigned short* WkAl = WkA_h + (size_t)l * 20480;
        const unsigned short* WvAl = WvA_h + (size_t)l * 20480;
        const unsigned short* WkBl = WkB_h + (size_t)l * 7168;
        const unsigned short* WvBl = WvB_h + (size_t)l * 7168;
        const unsigned short* Wq0l = Wq0_h + (size_t)l * 16384;
        const unsigned short* Wq1l = Wq1_h + (size_t)l * 1024;
        const float* Wo0l = Wo0 + (size_t)l * 128 * 128;
        const float* Wo1l = Wo1 + (size_t)l * 32 * 32;
        const float* Wf0al = Wf0a + (size_t)l * 512 * 128;
        const float* Wf0bl = Wf0b + (size_t)l * 128 * 512;
        const float* Wf1al = Wf1a + (size_t)l * 128 * 32;
        const float* Wf1bl = Wf1b + (size_t)l * 32 * 128;

        fnorm_kernel<<<NN / 4, 256, 0, stream>>>(f0, f1p,
            ln0_g + l * 128, ln0_b + l * 128, n1_g + l * 32, n1_b + l * 32,
            x0, x1p, x0h, x1h);

        radial_mfma<<<dim3(ENUM / 128, 12, 2), 256, 0, stream>>>(
            edges_h, WrKl, WrVl, x0, x1p, idx, y1, in0h, inUh, inWh);

        {   // hgemmA: k0(K,V), u(K,V), q0, q1 planes
            HJobs js; js.n = 8;
            js.j[0] = mkh(in0h,                       WkAl, k0, 128, 128, 160, 160, 160, 128, 0);
            js.j[1] = mkh(in0h + (size_t)ENUM * 160,  WvAl, v0, 128, 128, 160, 160, 160, 128, 0);
            js.j[2] = mkh(inUh,                       WkBl, u,             128, 32, 128, 128, 224, 32, 0);
            js.j[3] = mkh(inUh + (size_t)ENUM * 128,  WvBl, u + ENUM * 32, 128, 32, 128, 128, 224, 32, 0);
            js.j[4] = mkh(x0h, Wq0l, q0, 8, 128, 128, 128, 128, 128, 0);
            js.j[5] = mkh(x1h + 0 * X1HS, Wq1l, q1p + 0 * PL, 8, 32, 32, 32, 32, 32, 0);
            js.j[6] = mkh(x1h + 1 * X1HS, Wq1l, q1p + 1 * PL, 8, 32, 32, 32, 32, 32, 0);
            js.j[7] = mkh(x1h + 2 * X1HS, Wq1l, q1p + 2 * PL, 8, 32, 32, 32, 32, 32, 0);
            hgemm_multi<<<1336, 256, 0, stream>>>(js, y1);
        }
        {   // hgemmB: k1(K,V) with rank-1 u*y epilogue
            HJobs js; js.n = 2;
            js.j[0] = mkh(inWh,                          WkBl + 128, k1, 384, 32, 96, 96, 224, 32, 1, u);
            js.j[1] = mkh(inWh + (size_t)3 * ENUM * 96,  WvBl + 128, v1, 384, 32, 96, 96, 224, 32, 1, u + ENUM * 32);
            hgemm_multi<<<768, 256, 0, stream>>>(js, y1);
        }
        attn_core<<<NN / 4, 256, 0, stream>>>(q0, q1p, k0, k1, v0, v1,
            biasb + (size_t)l * ENUM * 4, maskf, o0, o1p);
        {   // output projections + rezero residual
            GJobs js; js.n = 4;
            js.j[0] = mkg(o0, Wo0l, f0, 128, 128, 128, 128, 128, 8, 16, 3, alpha_attn + l);
            js.j[1] = mkg(o1p + 0 * PL, Wo1l, f1p + 0 * PL, 32, 32, 32, 32, 32, 8, 8, 3, alpha_attn + l);
            js.j[2] = mkg(o1p + 1 * PL, Wo1l, f1p + 1 * PL, 32, 32, 32, 32, 32, 8, 8, 3, alpha_attn + l);
            js.j[3] = mkg(o1p + 2 * PL, Wo1l, f1p + 2 * PL, 32, 32, 32, 32, 32, 8, 8, 3, alpha_attn + l);
            gemm_multi<64, 4><<<40, 256, 0, stream>>>(js);
        }
        fnorm_kernel<<<NN / 4, 256, 0, stream>>>(f0, f1p,
            lnf0_g + l * 128, lnf0_b + l * 128, nf1_g + l * 32, nf1_b + l * 32,
            x0, x1p, nullptr, nullptr);
        {   // ff gemm1
            GJobs js; js.n = 4;
            js.j[0] = mkg(x0, Wf0al, h0, 512, 128, 128, 128, 512, 8, 64, 2);
            js.j[1] = mkg(x1p + 0 * PL, Wf1al, h1t + 0 * HPL, 128, 32, 32, 32, 128, 8, 16, 0);
            js.j[2] = mkg(x1p + 1 * PL, Wf1al, h1t + 1 * HPL, 128, 32, 32, 32, 128, 8, 16, 0);
            js.j[3] = mkg(x1p + 2 * PL, Wf1al, h1t + 2 * HPL, 128, 32, 32, 32, 128, 8, 16, 0);
            gemm_multi<64, 4><<<112, 256, 0, stream>>>(js);
        }
        {   // ff gemm2
            GJobs js; js.n = 4;
            js.j[0] = mkg(h0, Wf0bl, f0, 128, 512, 512, 512, 128, 8, 16, 3, alpha_ff + l);
            js.j[1] = mkg(h1t, Wf1bl, f1p + 0 * PL, 32, 128, 128, 128, 32, 8, 8, 3, alpha_ff + l, 0);
            js.j[2] = mkg(h1t, Wf1bl, f1p + 1 * PL, 32, 128, 128, 128, 32, 8, 8, 3, alpha_ff + l, 1);
            js.j[3] = mkg(h1t, Wf1bl, f1p + 2 * PL, 32, 128, 128, 128, 32, 8, 8, 3, alpha_ff + l, 2);
            gemm_multi<64, 4><<<40, 256, 0, stream>>>(js);
        }
    }

    {   // node_out = f0 @ Wp0^T
        GJobs js; js.n = 1;
        js.j[0] = mkg(f0, Wp0, out, 128, 128, 128, 128, 128, 8, 16, 0);
        gemm_multi<64, 4><<<16, 256, 0, stream>>>(js);
    }
    out_c_kernel<<<(NN * 9 + 255) / 256, 256, 0, stream>>>(f1p, coords, Wp1, out);
}

// Round 5
// 282.217 us; speedup vs baseline: 7.5708x; 1.5125x over previous
//
#include <hip/hip_runtime.h>
#include <hip/hip_bf16.h>
#include <math.h>

// ---- problem constants ----
static constexpr int NN  = 1024;
static constexpr int KK  = 16;
static constexpr int C0c = 128;
static constexpr int C1c = 32;
static constexpr int EDc = 64;
static constexpr int Lc  = 2;
static constexpr int ENUM = NN * KK;        // 16384 edges
static constexpr int PL   = NN * C1c;       // f32 plane stride
static constexpr int X1HS = NN * 32;        // bf16 x1 plane stride
#define SCALE_ATTN 0.13363062095621219f     /* 1/sqrt(32+3*8) */

typedef __attribute__((ext_vector_type(8))) short s8v;   // 8 bf16
typedef __attribute__((ext_vector_type(4))) float f4v;   // MFMA acc

__device__ __forceinline__ float wsum64(float v) {
    for (int o = 32; o > 0; o >>= 1) v += __shfl_xor(v, o);
    return v;
}
__device__ __forceinline__ float gsum16(float v) {
    for (int o = 8; o > 0; o >>= 1) v += __shfl_xor(v, o, 16);
    return v;
}
__device__ __forceinline__ float gmax16(float v) {
    for (int o = 8; o > 0; o >>= 1) v = fmaxf(v, __shfl_xor(v, o, 16));
    return v;
}
__device__ __forceinline__ float gelu_f(float x) {
    float x3 = x * x * x;
    return 0.5f * x * (1.0f + tanhf(0.7978845608028654f * (x + 0.044715f * x3)));
}
__device__ __forceinline__ unsigned short f2bf(float x) {
    union { float f; unsigned int u; } v; v.f = x;
    unsigned int r = v.u + 0x7fffu + ((v.u >> 16) & 1u);
    return (unsigned short)(r >> 16);
}
__device__ __forceinline__ float bf2f(unsigned short u) {
    union { float f; unsigned int i; } v; v.i = ((unsigned int)u) << 16;
    return v.f;
}
__device__ __forceinline__ s8v ld8(const unsigned short* p) { return *(const s8v*)p; }
__device__ __forceinline__ f4v mfma16(s8v a, s8v b, f4v c) {
    return __builtin_amdgcn_mfma_f32_16x16x32_bf16(a, b, c, 0, 0, 0);
}

// ---------------- f32 -> bf16 conversion (weights + node feats) ----------------
struct CvJob { const float* s; unsigned short* d; int n; };
struct CvJobs { CvJob j[20]; int n; int total; };
__global__ __launch_bounds__(256) void cvt_kernel(CvJobs js) {
    int g = blockIdx.x * 256 + threadIdx.x;
    if (g >= js.total) return;
    for (int i = 0; i < js.n; ++i) {
        int n = js.j[i].n;
        if (g < n) { js.j[i].d[g] = f2bf(js.j[i].s[g]); return; }
        g -= n;
    }
}

// ---------------- kNN: wave per node ----------------
__global__ __launch_bounds__(256) void knn_kernel2(const float* __restrict__ coords,
                                                   int* __restrict__ idx,
                                                   float* __restrict__ maskf,
                                                   float* __restrict__ y1) {
    __shared__ float ca[NN * 3];
    const int tid = threadIdx.x;
    for (int f = tid; f < NN * 3; f += 256) {
        int i = f / 3, m = f % 3;
        ca[f] = coords[(i * 4 + 1) * 3 + m];
    }
    __syncthreads();
    const int wid = tid >> 6, lane = tid & 63;
    const int n = blockIdx.x * 4 + wid;
    const float cx = ca[n * 3 + 0], cy = ca[n * 3 + 1], cz = ca[n * 3 + 2];
    float d[16];
#pragma unroll
    for (int s = 0; s < 16; ++s) {
        int i = s * 64 + lane;
        float dx = cx - ca[i * 3 + 0], dy = cy - ca[i * 3 + 1], dz = cz - ca[i * 3 + 2];
        float d2 = dx * dx + dy * dy + dz * dz;
        d[s] = (i == n) ? 1e9f : d2;
    }
    for (int t = 0; t < KK; ++t) {
        float best = 1e30f; int bi = 0;
#pragma unroll
        for (int s = 0; s < 16; ++s) {
            int i = s * 64 + lane;
            float v = d[s];
            if (v < best || (v == best && i < bi)) { best = v; bi = i; }
        }
#pragma unroll
        for (int o = 32; o > 0; o >>= 1) {
            float ov = __shfl_xor(best, o);
            int   oi = __shfl_xor(bi, o);
            if (ov < best || (ov == best && oi < bi)) { best = ov; bi = oi; }
        }
        const int j = bi;
        if (lane == 0) {
            idx[n * KK + t] = j;
            float dist = sqrtf(best);
            maskf[n * KK + t] = (dist <= 16.0f) ? 1.0f : 0.0f;
            float rx = ca[j * 3 + 0] - cx, ry = ca[j * 3 + 1] - cy, rz = ca[j * 3 + 2] - cz;
            float nrm = sqrtf(rx * rx + ry * ry + rz * rz) + 1e-6f;
            y1[(n * KK + t) * 3 + 0] = rx / nrm;
            y1[(n * KK + t) * 3 + 1] = ry / nrm;
            y1[(n * KK + t) * 3 + 2] = rz / nrm;
        }
        const int js = j >> 6, jl = j & 63;
#pragma unroll
        for (int s = 0; s < 16; ++s)
            if (s == js && jl == lane) d[s] = 2e30f;
    }
}

// ---------------- edge gather + LN (bf16) + attn bias (both layers) ----------------
__global__ __launch_bounds__(256) void edge_ln_kernel(const float* __restrict__ pair,
                                                      const int* __restrict__ idx,
                                                      const float* __restrict__ g,
                                                      const float* __restrict__ b,
                                                      const float* __restrict__ Wb,
                                                      unsigned short* __restrict__ edges_h,
                                                      float* __restrict__ biasb) {
    const int wid = threadIdx.x >> 6, lane = threadIdx.x & 63;
    const int e = blockIdx.x * 4 + wid;
    const int n = e >> 4;
    const int j = idx[e];
    float v = pair[((size_t)n * NN + j) * EDc + lane];
    float m = wsum64(v) * (1.0f / 64.0f);
    float d = v - m;
    float var = wsum64(d * d) * (1.0f / 64.0f);
    float nv = d * rsqrtf(var + 1e-5f) * g[lane] + b[lane];
    edges_h[e * EDc + lane] = f2bf(nv);
#pragma unroll
    for (int l = 0; l < 2; ++l)
#pragma unroll
        for (int h = 0; h < 4; ++h) {
            float t = wsum64(nv * Wb[(l * 4 + h) * 64 + lane]);
            if (lane == 0) biasb[(size_t)l * ENUM * 4 + e * 4 + h] = t;
        }
}

// ---------------- f1 input projection ----------------
__global__ __launch_bounds__(256) void f1init_kernel(const float* __restrict__ coords,
                                                     const float* __restrict__ Wi1,
                                                     float* __restrict__ f1p) {
    int g = blockIdx.x * 256 + threadIdx.x;
    if (g >= NN * 32) return;
    int n = g >> 5, c = g & 31;
    float w0 = Wi1[c * 3 + 0], w1 = Wi1[c * 3 + 1], w2 = Wi1[c * 3 + 2];
#pragma unroll
    for (int m = 0; m < 3; ++m) {
        float cav = coords[(n * 4 + 1) * 3 + m];
        float a0 = coords[(n * 4 + 0) * 3 + m] - cav;
        float a1 = coords[(n * 4 + 2) * 3 + m] - cav;
        float a2 = coords[(n * 4 + 3) * 3 + m] - cav;
        f1p[m * PL + n * 32 + c] = w0 * a0 + w1 * a1 + w2 * a2;
    }
}

// ---------------- standalone fiber norm (layer 0 entry) -> bf16 x ----------------
__global__ __launch_bounds__(256) void fnorm1_kernel(const float* __restrict__ f0,
                                                     const float* __restrict__ f1p,
                                                     const float* __restrict__ g0,
                                                     const float* __restrict__ b0,
                                                     const float* __restrict__ g1,
                                                     const float* __restrict__ b1,
                                                     unsigned short* __restrict__ x0h,
                                                     unsigned short* __restrict__ x1h) {
    const int wid = threadIdx.x >> 6, lane = threadIdx.x & 63;
    const int n = blockIdx.x * 4 + wid;
    float va = f0[n * 128 + lane], vb = f0[n * 128 + lane + 64];
    float m = wsum64(va + vb) * (1.0f / 128.0f);
    float da = va - m, db = vb - m;
    float var = wsum64(da * da + db * db) * (1.0f / 128.0f);
    float rs = rsqrtf(var + 1e-5f);
    x0h[n * 128 + lane]      = f2bf(gelu_f(da * rs * g0[lane] + b0[lane]));
    x0h[n * 128 + lane + 64] = f2bf(gelu_f(db * rs * g0[lane + 64] + b0[lane + 64]));
    int c = lane & 31;
    float h0 = f1p[0 * PL + n * 32 + c];
    float h1 = f1p[1 * PL + n * 32 + c];
    float h2 = f1p[2 * PL + n * 32 + c];
    float n1 = sqrtf(h0 * h0 + h1 * h1 + h2 * h2);
    float ms = wsum64(n1) * (1.0f / 64.0f);
    float dd = n1 - ms;
    float vv = wsum64(dd * dd) * (1.0f / 64.0f);
    float sc = gelu_f(dd * rsqrtf(vv + 1e-5f) * g1[c] + b1[c]) / (n1 + 1e-6f);
    if (lane < 32) {
        x1h[0 * X1HS + n * 32 + c] = f2bf(h0 * sc);
        x1h[1 * X1HS + n * 32 + c] = f2bf(h1 * sc);
        x1h[2 * X1HS + n * 32 + c] = f2bf(h2 * sc);
    }
}

// =====================================================================
//  Radial MFMA GEMM (K&V on blockIdx.z) with TFN pointwise epilogue.
// =====================================================================
__global__ __launch_bounds__(256) void radial_mfma(const unsigned short* __restrict__ edges_h,
                                                   const unsigned short* __restrict__ WrK_h,
                                                   const unsigned short* __restrict__ WrV_h,
                                                   const unsigned short* __restrict__ x0h,
                                                   const unsigned short* __restrict__ x1h,
                                                   const int* __restrict__ idx,
                                                   const float* __restrict__ y1,
                                                   unsigned short* __restrict__ in0,
                                                   unsigned short* __restrict__ inU,
                                                   unsigned short* __restrict__ inW) {
    const int t = threadIdx.x, w = t >> 6, l = t & 63;
    const int s = blockIdx.z;
    const unsigned short* Wr = s ? WrV_h : WrK_h;
    unsigned short* in0s = in0 + (size_t)s * ENUM * 160;
    unsigned short* inUs = inU + (size_t)s * ENUM * 128;
    unsigned short* inWs = inW + (size_t)s * 3 * ENUM * 96;
    const int e0w = blockIdx.x * 128 + w * 32;
    const int r0 = blockIdx.y * 32;
    const int c16 = l & 15, g8 = (l >> 4) * 8, g4 = (l >> 4) * 4;
    f4v acc[2][2];
#pragma unroll
    for (int a = 0; a < 2; ++a)
#pragma unroll
        for (int bq = 0; bq < 2; ++bq) acc[a][bq] = f4v{0.f, 0.f, 0.f, 0.f};
#pragma unroll
    for (int kc = 0; kc < 64; kc += 32) {
        s8v a0 = ld8(edges_h + (size_t)(e0w + c16) * 64 + kc + g8);
        s8v a1 = ld8(edges_h + (size_t)(e0w + 16 + c16) * 64 + kc + g8);
        s8v b0 = ld8(Wr + (size_t)(r0 + c16) * 64 + kc + g8);
        s8v b1 = ld8(Wr + (size_t)(r0 + 16 + c16) * 64 + kc + g8);
        acc[0][0] = mfma16(a0, b0, acc[0][0]);
        acc[0][1] = mfma16(a0, b1, acc[0][1]);
        acc[1][0] = mfma16(a1, b0, acc[1][0]);
        acc[1][1] = mfma16(a1, b1, acc[1][1]);
    }
#pragma unroll
    for (int fm = 0; fm < 2; ++fm)
#pragma unroll
        for (int r = 0; r < 4; ++r) {
            const int e = e0w + fm * 16 + g4 + r;
            const int j = idx[e];
            float ya = y1[e * 3 + 0], yb = y1[e * 3 + 1], yc = y1[e * 3 + 2];
#pragma unroll
            for (int fn = 0; fn < 2; ++fn) {
                const float av = acc[fm][fn][r];
                const int col = r0 + fn * 16 + c16;
                if (r0 < 128) {
                    in0s[(size_t)e * 160 + col] = f2bf(av * bf2f(x0h[j * 128 + col]));
                } else if (r0 < 160) {
                    int c = col - 128;
                    float d1 = bf2f(x1h[0 * X1HS + j * 32 + c]) * ya
                             + bf2f(x1h[1 * X1HS + j * 32 + c]) * yb
                             + bf2f(x1h[2 * X1HS + j * 32 + c]) * yc;
                    in0s[(size_t)e * 160 + col] = f2bf(av * d1);
                } else if (r0 < 288) {
                    int c = col - 160;
                    inUs[(size_t)e * 128 + c] = f2bf(av * bf2f(x0h[j * 128 + c]));
                } else {
                    int c = (r0 < 320) ? (col - 288) : (r0 < 352) ? (col - 320) : (col - 352);
                    float fx = bf2f(x1h[0 * X1HS + j * 32 + c]);
                    float fy = bf2f(x1h[1 * X1HS + j * 32 + c]);
                    float fz = bf2f(x1h[2 * X1HS + j * 32 + c]);
                    float w0, w1, w2; int off;
                    if (r0 < 320) {
                        off = 0; w0 = av * fx; w1 = av * fy; w2 = av * fz;
                    } else if (r0 < 352) {
                        off = 32;
                        w0 = av * (fy * yc - fz * yb);
                        w1 = av * (fz * ya - fx * yc);
                        w2 = av * (fx * yb - fy * ya);
                    } else {
                        off = 64;
                        float d1 = fx * ya + fy * yb + fz * yc;
                        w0 = av * (ya * d1 - fx * (1.0f / 3.0f));
                        w1 = av * (yb * d1 - fy * (1.0f / 3.0f));
                        w2 = av * (yc * d1 - fz * (1.0f / 3.0f));
                    }
                    inWs[((size_t)0 * ENUM + e) * 96 + off + c] = f2bf(w0);
                    inWs[((size_t)1 * ENUM + e) * 96 + off + c] = f2bf(w1);
                    inWs[((size_t)2 * ENUM + e) * 96 + off + c] = f2bf(w2);
                }
            }
        }
}

// =====================================================================
//  Multi-job bf16 MFMA GEMM: C[M,N] = A[M,K] @ B[N,K]^T.  Block = 128x32.
//  obf: 1 = bf16 C, 0 = f32 C.
// =====================================================================
struct HJob {
    const unsigned short* A; const unsigned short* B; void* C;
    int ntiles, mtiles, K, lda, ldb, ldc, obf, pad;
};
struct HJobs { HJob j[10]; int n; };

__global__ __launch_bounds__(256) void hgemm_multi(HJobs js) {
    const int t = threadIdx.x, w = t >> 6, l = t & 63;
    const int bid = blockIdx.x;
    HJob jb; int rel = 0;
    {
        int base = 0;
#pragma unroll 1
        for (int i = 0; i < js.n; ++i) {
            int nt = js.j[i].ntiles;
            if (bid >= base && bid < base + nt) { jb = js.j[i]; rel = bid - base; }
            base += nt;
        }
    }
    const int mt = rel % jb.mtiles, ntc = rel / jb.mtiles;
    const int m0 = mt * 128 + w * 32;
    const int n0 = ntc * 32;
    const int c16 = l & 15, g8 = (l >> 4) * 8, g4 = (l >> 4) * 4;
    f4v acc[2][2];
#pragma unroll
    for (int a = 0; a < 2; ++a)
#pragma unroll
        for (int bq = 0; bq < 2; ++bq) acc[a][bq] = f4v{0.f, 0.f, 0.f, 0.f};
    const unsigned short* Ap = jb.A + (size_t)(m0 + c16) * jb.lda + g8;
    const unsigned short* Bp = jb.B + (size_t)(n0 + c16) * jb.ldb + g8;
    for (int kc = 0; kc < jb.K; kc += 32) {
        s8v a0 = ld8(Ap + kc);
        s8v a1 = ld8(Ap + 16 * jb.lda + kc);
        s8v b0 = ld8(Bp + kc);
        s8v b1 = ld8(Bp + 16 * jb.ldb + kc);
        acc[0][0] = mfma16(a0, b0, acc[0][0]);
        acc[0][1] = mfma16(a0, b1, acc[0][1]);
        acc[1][0] = mfma16(a1, b0, acc[1][0]);
        acc[1][1] = mfma16(a1, b1, acc[1][1]);
    }
#pragma unroll
    for (int fm = 0; fm < 2; ++fm)
#pragma unroll
        for (int r = 0; r < 4; ++r) {
            const int m = m0 + fm * 16 + g4 + r;
#pragma unroll
            for (int fn = 0; fn < 2; ++fn) {
                const int n = n0 + fn * 16 + c16;
                float v = acc[fm][fn][r];
                if (jb.obf) ((unsigned short*)jb.C)[(size_t)m * jb.ldc + n] = f2bf(v);
                else        ((float*)jb.C)[(size_t)m * jb.ldc + n] = v;
            }
        }
}

// ---------------- attention core (u-rank1 fused; bf16 k/v; bf16 o out) ----------------
__global__ __launch_bounds__(256) void attn_core(const float* __restrict__ q0,
                                                 const float* __restrict__ q1p,
                                                 const unsigned short* __restrict__ k0h,
                                                 const unsigned short* __restrict__ k1ph,
                                                 const unsigned short* __restrict__ v0h,
                                                 const unsigned short* __restrict__ v1ph,
                                                 const unsigned short* __restrict__ uKh,
                                                 const unsigned short* __restrict__ uVh,
                                                 const float* __restrict__ biasb,
                                                 const float* __restrict__ maskf,
                                                 const float* __restrict__ y1,
                                                 unsigned short* __restrict__ o0h,
                                                 unsigned short* __restrict__ o1h) {
    __shared__ float q0s[4][128];
    __shared__ float q1s[4][96];
    __shared__ float attns[4][64];
    const int wid = threadIdx.x >> 6, lane = threadIdx.x & 63;
    const int n = blockIdx.x * 4 + wid;
    q0s[wid][lane]      = q0[n * 128 + lane];
    q0s[wid][lane + 64] = q0[n * 128 + lane + 64];
    if (lane < 32) {
#pragma unroll
        for (int m = 0; m < 3; ++m) q1s[wid][m * 32 + lane] = q1p[m * PL + n * 32 + lane];
    }
    __syncthreads();
    const int h = lane >> 4, k = lane & 15;
    const int e = n * KK + k;
    float acc = 0.f;
    const unsigned short* kr = k0h + (size_t)e * 128 + h * 32;
#pragma unroll
    for (int c8 = 0; c8 < 4; ++c8) {
        s8v kv = ld8(kr + c8 * 8);
#pragma unroll
        for (int j = 0; j < 8; ++j)
            acc += q0s[wid][h * 32 + c8 * 8 + j] * bf2f((unsigned short)kv[j]);
    }
    float yv[3] = {y1[e * 3 + 0], y1[e * 3 + 1], y1[e * 3 + 2]};
#pragma unroll
    for (int m = 0; m < 3; ++m) {
        const unsigned short* k1r = k1ph + ((size_t)m * ENUM + e) * 32 + h * 8;
        const unsigned short* ur  = uKh + (size_t)e * 32 + h * 8;
#pragma unroll
        for (int c = 0; c < 8; ++c)
            acc += q1s[wid][m * 32 + h * 8 + c] * (bf2f(k1r[c]) + bf2f(ur[c]) * yv[m]);
    }
    acc = acc * SCALE_ATTN + biasb[e * 4 + h];
    if (maskf[e] == 0.0f) acc = -1e9f;
    float mx = gmax16(acc);
    float ex = expf(acc - mx);
    float sm = gsum16(ex);
    attns[wid][lane] = ex / sm;
    __syncthreads();
#pragma unroll
    for (int t = 0; t < 2; ++t) {
        int oc = lane + 64 * t;
        int h2 = oc >> 5;
        float a = 0.f;
        for (int kk = 0; kk < KK; ++kk)
            a += attns[wid][h2 * 16 + kk] * bf2f(v0h[(size_t)(n * KK + kk) * 128 + oc]);
        o0h[(size_t)n * 128 + oc] = f2bf(a);
    }
    for (int val = lane; val < 96; val += 64) {
        int cc = val & 31, m = val >> 5;
        int h2 = cc >> 3;
        float a = 0.f;
        for (int kk = 0; kk < KK; ++kk) {
            int e2 = n * KK + kk;
            a += attns[wid][h2 * 16 + kk] *
                 (bf2f(v1ph[((size_t)m * ENUM + e2) * 32 + cc]) +
                  bf2f(uVh[(size_t)e2 * 32 + cc]) * y1[e2 * 3 + m]);
        }
        o1h[((size_t)m * NN + n) * 32 + cc] = f2bf(a);
    }
}

// =====================================================================
//  fused_post: o-proj + rezero residual + ff-prenorm + FF + residual,
//  then MODE0: next-layer fiber norm (-> x0h/x1h)  or  MODE1: output proj.
//  Block = 16 nodes, grid 64.
// =====================================================================
template <int MODE>
__global__ __launch_bounds__(256) void fused_post(
    const unsigned short* __restrict__ o0h, const unsigned short* __restrict__ o1h,
    float* __restrict__ f0, float* __restrict__ f1p,
    const unsigned short* __restrict__ Wo0h, const unsigned short* __restrict__ Wo1h,
    const unsigned short* __restrict__ Wf0ah, const unsigned short* __restrict__ Wf0bh,
    const unsigned short* __restrict__ Wf1ah, const unsigned short* __restrict__ Wf1bh,
    const float* __restrict__ alA, const float* __restrict__ alF,
    const float* __restrict__ lnf0_g, const float* __restrict__ lnf0_b,
    const float* __restrict__ nf1_g, const float* __restrict__ nf1_b,
    const float* __restrict__ ln0n_g, const float* __restrict__ ln0n_b,
    const float* __restrict__ n1n_g, const float* __restrict__ n1n_b,
    unsigned short* __restrict__ x0h, unsigned short* __restrict__ x1h,
    const unsigned short* __restrict__ Wp0h, const float* __restrict__ Wp1,
    const float* __restrict__ coords, float* __restrict__ out) {
    __shared__ float f0s[16][132];
    __shared__ float f1s[3][16][36];
    __shared__ unsigned short x0s[16][136];
    __shared__ float x1s[3][16][36];
    __shared__ unsigned short hs[16][520];
    __shared__ unsigned short h1b[3][16][136];
    const int t = threadIdx.x, w = t >> 6, l = t & 63;
    const int c16 = l & 15, g8 = (l >> 4) * 8, g4 = (l >> 4) * 4;
    const int n0 = blockIdx.x * 16;
    const float aA = alA[0], aF = alF[0];

    // ---- phase 1: o0 projection MFMA + residual -> f0s ----
    {
        f4v acc[2] = {f4v{0.f,0.f,0.f,0.f}, f4v{0.f,0.f,0.f,0.f}};
        const unsigned short* Ap = o0h + (size_t)(n0 + c16) * 128 + g8;
#pragma unroll
        for (int kc = 0; kc < 128; kc += 32) {
            s8v a = ld8(Ap + kc);
#pragma unroll
            for (int tt = 0; tt < 2; ++tt) {
                s8v b = ld8(Wo0h + (size_t)((w * 2 + tt) * 16 + c16) * 128 + g8 + kc);
                acc[tt] = mfma16(a, b, acc[tt]);
            }
        }
#pragma unroll
        for (int tt = 0; tt < 2; ++tt) {
            int colg = (w * 2 + tt) * 16 + c16;
#pragma unroll
            for (int r = 0; r < 4; ++r) {
                int row = g4 + r;
                f0s[row][colg] = f0[(size_t)(n0 + row) * 128 + colg] + aA * acc[tt][r];
            }
        }
    }
    // ---- phase 2: o1 projection VALU + residual -> f1s ----
#pragma unroll
    for (int it = 0; it < 6; ++it) {
        int g = t + it * 256;
        int c = g & 31, node = (g >> 5) & 15, m = g >> 9;
        float a = 0.f;
        const unsigned short* wrow = Wo1h + c * 32;
        const unsigned short* orow = o1h + ((size_t)m * NN + n0 + node) * 32;
#pragma unroll
        for (int cc = 0; cc < 32; ++cc) a += bf2f(wrow[cc]) * bf2f(orow[cc]);
        f1s[m][node][c] = f1p[(size_t)m * PL + (n0 + node) * 32 + c] + aA * a;
    }
    __syncthreads();
    // ---- phase 3: ff pre-norm (LN on f0s -> x0s bf16; n1-norm f1s -> x1s f32) ----
    for (int i = 0; i < 4; ++i) {
        int row = w * 4 + i;
        float v0 = f0s[row][l], v1 = f0s[row][l + 64];
        float mn = wsum64(v0 + v1) * (1.0f / 128.0f);
        float d0 = v0 - mn, d1 = v1 - mn;
        float var = wsum64(d0 * d0 + d1 * d1) * (1.0f / 128.0f);
        float rs = rsqrtf(var + 1e-5f);
        x0s[row][l]      = f2bf(gelu_f(d0 * rs * lnf0_g[l] + lnf0_b[l]));
        x0s[row][l + 64] = f2bf(gelu_f(d1 * rs * lnf0_g[l + 64] + lnf0_b[l + 64]));
    }
    {
        int node = t >> 4, sub = t & 15;
        float p[2][3], n1v[2];
#pragma unroll
        for (int q = 0; q < 2; ++q) {
            int c = sub + q * 16;
            p[q][0] = f1s[0][node][c]; p[q][1] = f1s[1][node][c]; p[q][2] = f1s[2][node][c];
            n1v[q] = sqrtf(p[q][0]*p[q][0] + p[q][1]*p[q][1] + p[q][2]*p[q][2]);
        }
        float s = gsum16(n1v[0] + n1v[1]);
        float mn = s * (1.0f / 32.0f);
        float d0 = n1v[0] - mn, d1 = n1v[1] - mn;
        float vv = gsum16(d0 * d0 + d1 * d1);
        float rs = rsqrtf(vv * (1.0f / 32.0f) + 1e-5f);
#pragma unroll
        for (int q = 0; q < 2; ++q) {
            int c = sub + q * 16;
            float sc = gelu_f((n1v[q] - mn) * rs * nf1_g[c] + nf1_b[c]) / (n1v[q] + 1e-6f);
            x1s[0][node][c] = p[q][0] * sc;
            x1s[1][node][c] = p[q][1] * sc;
            x1s[2][node][c] = p[q][2] * sc;
        }
    }
    __syncthreads();
    // ---- phase 4: ff1 MFMA (h = gelu(x0 @ Wf0a^T)) + VALU h1 path ----
    {
        f4v acc[8];
#pragma unroll
        for (int i = 0; i < 8; ++i) acc[i] = f4v{0.f,0.f,0.f,0.f};
#pragma unroll
        for (int kc = 0; kc < 128; kc += 32) {
            s8v a = *(const s8v*)&x0s[c16][kc + g8];
#pragma unroll
            for (int tt = 0; tt < 8; ++tt) {
                s8v b = ld8(Wf0ah + (size_t)((w * 8 + tt) * 16 + c16) * 128 + g8 + kc);
                acc[tt] = mfma16(a, b, acc[tt]);
            }
        }
#pragma unroll
        for (int tt = 0; tt < 8; ++tt) {
            int colg = (w * 8 + tt) * 16 + c16;
#pragma unroll
            for (int r = 0; r < 4; ++r) hs[g4 + r][colg] = f2bf(gelu_f(acc[tt][r]));
        }
    }
#pragma unroll
    for (int it = 0; it < 8; ++it) {
        int g = t + it * 256;
        int r = g & 127, node = g >> 7;
        float a0 = 0.f, a1 = 0.f, a2 = 0.f;
        const unsigned short* wrow = Wf1ah + r * 32;
#pragma unroll
        for (int c = 0; c < 32; ++c) {
            float wv = bf2f(wrow[c]);
            a0 += wv * x1s[0][node][c];
            a1 += wv * x1s[1][node][c];
            a2 += wv * x1s[2][node][c];
        }
        float nh = sqrtf(a0 * a0 + a1 * a1 + a2 * a2);
        float sc = gelu_f(nh) / (nh + 1e-6f);
        h1b[0][node][r] = f2bf(a0 * sc);
        h1b[1][node][r] = f2bf(a1 * sc);
        h1b[2][node][r] = f2bf(a2 * sc);
    }
    __syncthreads();
    // ---- phase 5: ff2 MFMA + residual; VALU f1'' ----
    {
        f4v acc[2] = {f4v{0.f,0.f,0.f,0.f}, f4v{0.f,0.f,0.f,0.f}};
#pragma unroll 4
        for (int kc = 0; kc < 512; kc += 32) {
            s8v a = *(const s8v*)&hs[c16][kc + g8];
#pragma unroll
            for (int tt = 0; tt < 2; ++tt) {
                s8v b = ld8(Wf0bh + (size_t)((w * 2 + tt) * 16 + c16) * 512 + g8 + kc);
                acc[tt] = mfma16(a, b, acc[tt]);
            }
        }
#pragma unroll
        for (int tt = 0; tt < 2; ++tt) {
            int colg = (w * 2 + tt) * 16 + c16;
#pragma unroll
            for (int r = 0; r < 4; ++r) {
                int row = g4 + r;
                float v = f0s[row][colg] + aF * acc[tt][r];
                f0s[row][colg] = v;
                f0[(size_t)(n0 + row) * 128 + colg] = v;
            }
        }
    }
#pragma unroll
    for (int it = 0; it < 6; ++it) {
        int g = t + it * 256;
        int c = g & 31, node = (g >> 5) & 15, m = g >> 9;
        float a = 0.f;
        const unsigned short* wrow = Wf1bh + c * 128;
#pragma unroll 8
        for (int r = 0; r < 128; ++r) a += bf2f(wrow[r]) * bf2f(h1b[m][node][r]);
        float v = f1s[m][node][c] + aF * a;
        f1s[m][node][c] = v;
        f1p[(size_t)m * PL + (n0 + node) * 32 + c] = v;
    }
    __syncthreads();
    // ---- phase 6 ----
    if (MODE == 0) {
        for (int i = 0; i < 4; ++i) {
            int row = w * 4 + i;
            float v0 = f0s[row][l], v1 = f0s[row][l + 64];
            float mn = wsum64(v0 + v1) * (1.0f / 128.0f);
            float d0 = v0 - mn, d1 = v1 - mn;
            float var = wsum64(d0 * d0 + d1 * d1) * (1.0f / 128.0f);
            float rs = rsqrtf(var + 1e-5f);
            x0h[(size_t)(n0 + row) * 128 + l]      = f2bf(gelu_f(d0 * rs * ln0n_g[l] + ln0n_b[l]));
            x0h[(size_t)(n0 + row) * 128 + l + 64] = f2bf(gelu_f(d1 * rs * ln0n_g[l + 64] + ln0n_b[l + 64]));
        }
        {
            int node = t >> 4, sub = t & 15;
            float p[2][3], n1v[2];
#pragma unroll
            for (int q = 0; q < 2; ++q) {
                int c = sub + q * 16;
                p[q][0] = f1s[0][node][c]; p[q][1] = f1s[1][node][c]; p[q][2] = f1s[2][node][c];
                n1v[q] = sqrtf(p[q][0]*p[q][0] + p[q][1]*p[q][1] + p[q][2]*p[q][2]);
            }
            float s = gsum16(n1v[0] + n1v[1]);
            float mn = s * (1.0f / 32.0f);
            float d0 = n1v[0] - mn, d1 = n1v[1] - mn;
            float vv = gsum16(d0 * d0 + d1 * d1);
            float rs = rsqrtf(vv * (1.0f / 32.0f) + 1e-5f);
#pragma unroll
            for (int q = 0; q < 2; ++q) {
                int c = sub + q * 16;
                float sc = gelu_f((n1v[q] - mn) * rs * n1n_g[c] + n1n_b[c]) / (n1v[q] + 1e-6f);
                x1h[(size_t)0 * X1HS + (n0 + node) * 32 + c] = f2bf(p[q][0] * sc);
                x1h[(size_t)1 * X1HS + (n0 + node) * 32 + c] = f2bf(p[q][1] * sc);
                x1h[(size_t)2 * X1HS + (n0 + node) * 32 + c] = f2bf(p[q][2] * sc);
            }
        }
    } else {
        // final: out_node = f0'' @ Wp0^T ; out_coords = CA + Wp1 @ f1''
#pragma unroll
        for (int it = 0; it < 8; ++it) {
            int g = t + it * 256;
            int row = g >> 7, col = g & 127;
            x0s[row][col] = f2bf(f0s[row][col]);
        }
        __syncthreads();
        f4v acc[2] = {f4v{0.f,0.f,0.f,0.f}, f4v{0.f,0.f,0.f,0.f}};
#pragma unroll
        for (int kc = 0; kc < 128; kc += 32) {
            s8v a = *(const s8v*)&x0s[c16][kc + g8];
#pragma unroll
            for (int tt = 0; tt < 2; ++tt) {
                s8v b = ld8(Wp0h + (size_t)((w * 2 + tt) * 16 + c16) * 128 + g8 + kc);
                acc[tt] = mfma16(a, b, acc[tt]);
            }
        }
#pragma unroll
        for (int tt = 0; tt < 2; ++tt) {
            int colg = (w * 2 + tt) * 16 + c16;
#pragma unroll
            for (int r = 0; r < 4; ++r)
                out[(size_t)(n0 + g4 + r) * 128 + colg] = acc[tt][r];
        }
        if (t < 144) {
            int node = t / 9, rr = t % 9, o = rr / 3, m = rr % 3;
            float a = coords[((size_t)(n0 + node) * 4 + 1) * 3 + m];
            for (int c = 0; c < 32; ++c) a += Wp1[o * 32 + c] * f1s[m][node][c];
            out[NN * 128 + ((size_t)(n0 + node) * 3 + o) * 3 + m] = a;
        }
    }
}

static inline HJob mkh(const unsigned short* A, const unsigned short* B, void* C,
                       int mtiles, int ncols, int K, int lda, int ldb, int ldc, int obf) {
    HJob j; j.A = A; j.B = B; j.C = C;
    j.mtiles = mtiles; j.ntiles = mtiles * (ncols / 32); j.K = K;
    j.lda = lda; j.ldb = ldb; j.ldc = ldc; j.obf = obf; j.pad = 0;
    return j;
}

extern "C" void kernel_launch(void* const* d_in, const int* in_sizes, int n_in,
                              void* d_out, int out_size, void* d_ws, size_t ws_size,
                              hipStream_t stream) {
    (void)in_sizes; (void)n_in; (void)out_size; (void)ws_size;
    const float* node_feats = (const float*)d_in[0];
    const float* pair       = (const float*)d_in[1];
    const float* coords     = (const float*)d_in[2];
    const float* eln_g      = (const float*)d_in[3];
    const float* eln_b      = (const float*)d_in[4];
    const float* Wi0        = (const float*)d_in[5];
    const float* Wi1        = (const float*)d_in[6];
    const float* ln0_g      = (const float*)d_in[7];
    const float* ln0_b      = (const float*)d_in[8];
    const float* n1_g       = (const float*)d_in[9];
    const float* n1_b       = (const float*)d_in[10];
    const float* Wq0        = (const float*)d_in[11];
    const float* Wq1        = (const float*)d_in[12];
    const float* WrK        = (const float*)d_in[13];
    const float* WrV        = (const float*)d_in[14];
    const float* WkA        = (const float*)d_in[15];
    const float* WkB        = (const float*)d_in[16];
    const float* WvA        = (const float*)d_in[17];
    const float* WvB        = (const float*)d_in[18];
    const float* Wb         = (const float*)d_in[19];
    const float* Wo0        = (const float*)d_in[20];
    const float* Wo1        = (const float*)d_in[21];
    const float* alpha_attn = (const float*)d_in[22];
    const float* lnf0_g     = (const float*)d_in[23];
    const float* lnf0_b     = (const float*)d_in[24];
    const float* nf1_g      = (const float*)d_in[25];
    const float* nf1_b      = (const float*)d_in[26];
    const float* Wf0a       = (const float*)d_in[27];
    const float* Wf0b       = (const float*)d_in[28];
    const float* Wf1a       = (const float*)d_in[29];
    const float* Wf1b       = (const float*)d_in[30];
    const float* alpha_ff   = (const float*)d_in[31];
    const float* Wp0        = (const float*)d_in[32];
    const float* Wp1        = (const float*)d_in[33];
    float* out = (float*)d_out;

    float* ws = (float*)d_ws;
    size_t off = 0;
    int*   idx   = (int*)(ws + off); off += NN * KK;
    float* maskf = ws + off;         off += NN * KK;
    float* y1    = ws + off;         off += NN * KK * 3;
    float* f0    = ws + off;         off += NN * C0c;
    float* f1p   = ws + off;         off += 3 * PL;
    float* q0    = ws + off;         off += NN * C0c;
    float* q1p   = ws + off;         off += 3 * PL;
    float* biasb = ws + off;         off += (size_t)2 * ENUM * 4;
    off = (off + 3) & ~(size_t)3;
    unsigned short* up = (unsigned short*)(ws + off);
    size_t uo = 0;
    unsigned short* edges_h = up + uo; uo += (size_t)ENUM * 64;
    unsigned short* in0h    = up + uo; uo += (size_t)2 * ENUM * 160;
    unsigned short* inUh    = up + uo; uo += (size_t)2 * ENUM * 128;
    unsigned short* inWh    = up + uo; uo += (size_t)2 * 3 * ENUM * 96;
    unsigned short* x0h     = up + uo; uo += (size_t)NN * 128;
    unsigned short* x1h     = up + uo; uo += (size_t)3 * X1HS;
    unsigned short* nf_h    = up + uo; uo += (size_t)NN * 128;
    unsigned short* k0h     = up + uo; uo += (size_t)ENUM * 128;
    unsigned short* v0h     = up + uo; uo += (size_t)ENUM * 128;
    unsigned short* uKh     = up + uo; uo += (size_t)ENUM * 32;
    unsigned short* uVh     = up + uo; uo += (size_t)ENUM * 32;
    unsigned short* k1ph    = up + uo; uo += (size_t)3 * ENUM * 32;
    unsigned short* v1ph    = up + uo; uo += (size_t)3 * ENUM * 32;
    unsigned short* o0h     = up + uo; uo += (size_t)NN * 128;
    unsigned short* o1h     = up + uo; uo += (size_t)3 * NN * 32;
    unsigned short* WrK_h   = up + uo; uo += 2 * 24576;
    unsigned short* WrV_h   = up + uo; uo += 2 * 24576;
    unsigned short* WkA_h   = up + uo; uo += 2 * 20480;
    unsigned short* WvA_h   = up + uo; uo += 2 * 20480;
    unsigned short* WkB_h   = up + uo; uo += 2 * 7168;
    unsigned short* WvB_h   = up + uo; uo += 2 * 7168;
    unsigned short* Wq0_h   = up + uo; uo += 2 * 16384;
    unsigned short* Wq1_h   = up + uo; uo += 2 * 1024;
    unsigned short* Wo0_h   = up + uo; uo += 2 * 16384;
    unsigned short* Wo1_h   = up + uo; uo += 2 * 1024;
    unsigned short* Wf0a_h  = up + uo; uo += 2 * 65536;
    unsigned short* Wf0b_h  = up + uo; uo += 2 * 65536;
    unsigned short* Wf1a_h  = up + uo; uo += 2 * 4096;
    unsigned short* Wf1b_h  = up + uo; uo += 2 * 4096;
    unsigned short* Wp0_h   = up + uo; uo += 16384;
    unsigned short* Wi0_h   = up + uo; uo += 16384;

    {   // conversions
        CvJobs cj; cj.n = 17;
        cj.j[0]  = {WrK,  WrK_h,  2 * 24576};
        cj.j[1]  = {WrV,  WrV_h,  2 * 24576};
        cj.j[2]  = {WkA,  WkA_h,  2 * 20480};
        cj.j[3]  = {WvA,  WvA_h,  2 * 20480};
        cj.j[4]  = {WkB,  WkB_h,  2 * 7168};
        cj.j[5]  = {WvB,  WvB_h,  2 * 7168};
        cj.j[6]  = {Wq0,  Wq0_h,  2 * 16384};
        cj.j[7]  = {Wq1,  Wq1_h,  2 * 1024};
        cj.j[8]  = {Wo0,  Wo0_h,  2 * 16384};
        cj.j[9]  = {Wo1,  Wo1_h,  2 * 1024};
        cj.j[10] = {Wf0a, Wf0a_h, 2 * 65536};
        cj.j[11] = {Wf0b, Wf0b_h, 2 * 65536};
        cj.j[12] = {Wf1a, Wf1a_h, 2 * 4096};
        cj.j[13] = {Wf1b, Wf1b_h, 2 * 4096};
        cj.j[14] = {Wp0,  Wp0_h,  16384};
        cj.j[15] = {Wi0,  Wi0_h,  16384};
        cj.j[16] = {node_feats, nf_h, NN * 128};
        cj.total = 2*24576*2 + 2*20480*2 + 2*7168*2 + 2*16384 + 2*1024 + 2*16384
                 + 2*1024 + 2*65536*2 + 2*4096*2 + 16384 + 16384 + NN*128;
        cvt_kernel<<<(cj.total + 255) / 256, 256, 0, stream>>>(cj);
    }
    knn_kernel2<<<NN / 4, 256, 0, stream>>>(coords, idx, maskf, y1);
    f1init_kernel<<<(NN * 32 + 255) / 256, 256, 0, stream>>>(coords, Wi1, f1p);
    edge_ln_kernel<<<ENUM / 4, 256, 0, stream>>>(pair, idx, eln_g, eln_b, Wb, edges_h, biasb);
    {   // f0 = node_feats @ Wi0^T
        HJobs js; js.n = 1;
        js.j[0] = mkh(nf_h, Wi0_h, f0, 8, 128, 128, 128, 128, 128, 0);
        hgemm_multi<<<32, 256, 0, stream>>>(js);
    }
    fnorm1_kernel<<<NN / 4, 256, 0, stream>>>(f0, f1p, ln0_g, ln0_b, n1_g, n1_b, x0h, x1h);

    for (int l = 0; l < Lc; ++l) {
        const unsigned short* WrKl = WrK_h + (size_t)l * 24576;
        const unsigned short* WrVl = WrV_h + (size_t)l * 24576;
        const unsigned short* WkAl = WkA_h + (size_t)l * 20480;
        const unsigned short* WvAl = WvA_h + (size_t)l * 20480;
        const unsigned short* WkBl = WkB_h + (size_t)l * 7168;
        const unsigned short* WvBl = WvB_h + (size_t)l * 7168;

        radial_mfma<<<dim3(ENUM / 128, 12, 2), 256, 0, stream>>>(
            edges_h, WrKl, WrVl, x0h, x1h, idx, y1, in0h, inUh, inWh);

        {   // mega GEMM: k0, v0, uK, uV, k1p, v1p, q0, q1 planes
            HJobs js; js.n = 10;
            js.j[0] = mkh(in0h,                        WkAl, k0h, 128, 128, 160, 160, 160, 128, 1);
            js.j[1] = mkh(in0h + (size_t)ENUM * 160,   WvAl, v0h, 128, 128, 160, 160, 160, 128, 1);
            js.j[2] = mkh(inUh,                        WkBl, uKh, 128, 32, 128, 128, 224, 32, 1);
            js.j[3] = mkh(inUh + (size_t)ENUM * 128,   WvBl, uVh, 128, 32, 128, 128, 224, 32, 1);
            js.j[4] = mkh(inWh,                        WkBl + 128, k1ph, 384, 32, 96, 96, 224, 32, 1);
            js.j[5] = mkh(inWh + (size_t)3 * ENUM * 96, WvBl + 128, v1ph, 384, 32, 96, 96, 224, 32, 1);
            js.j[6] = mkh(x0h, Wq0_h + (size_t)l * 16384, q0, 8, 128, 128, 128, 128, 128, 0);
            js.j[7] = mkh(x1h + 0 * X1HS, Wq1_h + (size_t)l * 1024, q1p + 0 * PL, 8, 32, 32, 32, 32, 32, 0);
            js.j[8] = mkh(x1h + 1 * X1HS, Wq1_h + (size_t)l * 1024, q1p + 1 * PL, 8, 32, 32, 32, 32, 32, 0);
            js.j[9] = mkh(x1h + 2 * X1HS, Wq1_h + (size_t)l * 1024, q1p + 2 * PL, 8, 32, 32, 32, 32, 32, 0);
            hgemm_multi<<<2104, 256, 0, stream>>>(js);
        }
        attn_core<<<NN / 4, 256, 0, stream>>>(q0, q1p, k0h, k1ph, v0h, v1ph, uKh, uVh,
            biasb + (size_t)l * ENUM * 4, maskf, y1, o0h, o1h);
        if (l == 0) {
            fused_post<0><<<NN / 16, 256, 0, stream>>>(
                o0h, o1h, f0, f1p,
                Wo0_h, Wo1_h, Wf0a_h, Wf0b_h, Wf1a_h, Wf1b_h,
                alpha_attn + 0, alpha_ff + 0,
                lnf0_g, lnf0_b, nf1_g, nf1_b,
                ln0_g + 128, ln0_b + 128, n1_g + 32, n1_b + 32,
                x0h, x1h, nullptr, nullptr, nullptr, nullptr);
        } else {
            fused_post<1><<<NN / 16, 256, 0, stream>>>(
                o0h, o1h, f0, f1p,
                Wo0_h + 16384, Wo1_h + 1024, Wf0a_h + 65536, Wf0b_h + 65536,
                Wf1a_h + 4096, Wf1b_h + 4096,
                alpha_attn + 1, alpha_ff + 1,
                lnf0_g + 128, lnf0_b + 128, nf1_g + 32, nf1_b + 32,
                nullptr, nullptr, nullptr, nullptr,
                nullptr, nullptr, Wp0_h, Wp1, coords, out);
        }
    }
}